// Round 1
// baseline (1700.554 us; speedup 1.0000x reference)
//
#include <hip/hip_runtime.h>

#define NN 100000   // nodes
#define NE 600000   // edges
#define NG 4096     // graphs
#define FIN 74
#define HD 128
#define NL 3
#define BN_EPS 1e-5f

// ---------------- degree / norm ----------------
__global__ __launch_bounds__(256) void k_deg(const int* __restrict__ dst,
                                             float* __restrict__ deg) {
    int e = blockIdx.x * 256 + threadIdx.x;
    if (e < NE) atomicAdd(&deg[dst[e]], 1.0f);
}

__global__ __launch_bounds__(256) void k_dinv(float* __restrict__ deg) {
    int n = blockIdx.x * 256 + threadIdx.x;
    if (n < NN) deg[n] = rsqrtf(deg[n] + 1.0f);  // +1 self-loop; always >= 1
}

// ---------------- embedding GEMM: h = relu(x @ W + b), K=74 ----------------
__global__ __launch_bounds__(128) void k_emb(const float* __restrict__ x,
                                             const float* __restrict__ W,
                                             const float* __restrict__ b,
                                             float* __restrict__ h) {
    __shared__ float xs[8][FIN];
    int c = threadIdx.x;
    int n0 = blockIdx.x * 8;
    for (int idx = c; idx < 8 * FIN; idx += 128) {
        int j = idx / FIN, k = idx % FIN;
        int n = n0 + j;
        xs[j][k] = (n < NN) ? x[n * FIN + k] : 0.0f;
    }
    __syncthreads();
    float bias = b[c];
    float acc[8];
#pragma unroll
    for (int j = 0; j < 8; j++) acc[j] = bias;
    for (int k = 0; k < FIN; k++) {
        float w = W[k * HD + c];
#pragma unroll
        for (int j = 0; j < 8; j++) acc[j] += xs[j][k] * w;
    }
#pragma unroll
    for (int j = 0; j < 8; j++) {
        int n = n0 + j;
        if (n < NN) h[n * HD + c] = fmaxf(acc[j], 0.0f);
    }
}

// ---------------- conv GEMM: hw = h @ W, K=128 ----------------
__global__ __launch_bounds__(128) void k_conv(const float* __restrict__ hin,
                                              const float* __restrict__ W,
                                              float* __restrict__ hw) {
    __shared__ float hs[8][HD];
    int c = threadIdx.x;
    int n0 = blockIdx.x * 8;
#pragma unroll
    for (int j = 0; j < 8; j++) {
        int n = n0 + j;
        hs[j][c] = (n < NN) ? hin[n * HD + c] : 0.0f;
    }
    __syncthreads();
    float acc[8] = {0.f, 0.f, 0.f, 0.f, 0.f, 0.f, 0.f, 0.f};
    for (int k = 0; k < HD; k++) {
        float w = W[k * HD + c];
#pragma unroll
        for (int j = 0; j < 8; j++) acc[j] += hs[j][k] * w;
    }
#pragma unroll
    for (int j = 0; j < 8; j++) {
        int n = n0 + j;
        if (n < NN) hw[n * HD + c] = acc[j];
    }
}

// ---------------- scatter init: out = hw * dinv^2 (self loop) + bias ----------------
__global__ __launch_bounds__(256) void k_scatter_init(const float* __restrict__ hw,
                                                      const float* __restrict__ dinv,
                                                      const float* __restrict__ bias,
                                                      float* __restrict__ out) {
    int idx = blockIdx.x * 256 + threadIdx.x;
    if (idx >= NN * HD) return;
    int n = idx >> 7;
    int c = idx & 127;
    float d = dinv[n];
    out[idx] = hw[idx] * d * d + bias[c];
}

// ---------------- edge scatter: out[dst] += hw[src] * dinv[src]*dinv[dst] ----------------
__global__ __launch_bounds__(256) void k_edge(const int* __restrict__ src,
                                              const int* __restrict__ dst,
                                              const float* __restrict__ dinv,
                                              const float* __restrict__ hw,
                                              float* __restrict__ out) {
    int idx = blockIdx.x * 256 + threadIdx.x;
    if (idx >= NE * HD) return;
    int e = idx >> 7;
    int c = idx & 127;
    int s = src[e], d = dst[e];
    float nm = dinv[s] * dinv[d];
    atomicAdd(&out[d * HD + c], hw[s * HD + c] * nm);
}

// ---------------- BN statistics ----------------
__global__ __launch_bounds__(128) void k_bn_stats(const float* __restrict__ h,
                                                  float* __restrict__ sums) {
    int c = threadIdx.x;
    int chunk = (NN + gridDim.x - 1) / gridDim.x;
    int n0 = blockIdx.x * chunk;
    int n1 = min(n0 + chunk, NN);
    float s = 0.f, sq = 0.f;
    for (int n = n0; n < n1; n++) {
        float v = h[n * HD + c];
        s += v;
        sq += v * v;
    }
    atomicAdd(&sums[c], s);
    atomicAdd(&sums[HD + c], sq);
}

__global__ __launch_bounds__(128) void k_bn_fin(const float* __restrict__ sums,
                                                const float* __restrict__ gamma,
                                                const float* __restrict__ beta,
                                                float* __restrict__ ss) {
    int c = threadIdx.x;
    float inv_n = 1.0f / (float)NN;
    float mu = sums[c] * inv_n;
    float var = sums[HD + c] * inv_n - mu * mu;
    float sc = gamma[c] * rsqrtf(var + BN_EPS);
    ss[c] = sc;
    ss[HD + c] = beta[c] - mu * sc;
}

__global__ __launch_bounds__(256) void k_bn_apply(float* __restrict__ h,
                                                  const float* __restrict__ ss) {
    int idx = blockIdx.x * 256 + threadIdx.x;
    if (idx >= NN * HD) return;
    int c = idx & 127;
    h[idx] = fmaxf(h[idx] * ss[c] + ss[HD + c], 0.0f);
}

// ---------------- pooling ----------------
__global__ __launch_bounds__(256) void k_pool(const float* __restrict__ h,
                                              const int* __restrict__ batch,
                                              float* __restrict__ psum,
                                              float* __restrict__ pmax) {
    int idx = blockIdx.x * 256 + threadIdx.x;
    if (idx >= NN * HD) return;
    int n = idx >> 7;
    int c = idx & 127;
    int g = batch[n];
    float v = h[idx];
    atomicAdd(&psum[g * HD + c], v);
    // h >= 0 post-ReLU: uint bit-pattern order == float order; 0-init matches
    // the reference's empty-segment guard (-inf -> 0).
    atomicMax((unsigned int*)&pmax[g * HD + c], __float_as_uint(v));
}

__global__ __launch_bounds__(256) void k_cnt(const int* __restrict__ batch,
                                             float* __restrict__ cnt) {
    int n = blockIdx.x * 256 + threadIdx.x;
    if (n < NN) atomicAdd(&cnt[batch[n]], 1.0f);
}

__global__ __launch_bounds__(256) void k_pool_fin(const float* __restrict__ psum,
                                                  const float* __restrict__ pmax,
                                                  const float* __restrict__ cnt,
                                                  float* __restrict__ gfeat) {
    int idx = blockIdx.x * 256 + threadIdx.x;
    if (idx >= NG * HD) return;
    int g = idx >> 7;
    int c = idx & 127;
    float ct = fmaxf(cnt[g], 1.0f);
    gfeat[g * (2 * HD) + c] = psum[idx] / ct;
    gfeat[g * (2 * HD) + HD + c] = pmax[idx];
}

// ---------------- fused MLP head ----------------
__global__ __launch_bounds__(128) void k_mlp(const float* __restrict__ gfeat,
                                             const float* __restrict__ w1,
                                             const float* __restrict__ b1,
                                             const float* __restrict__ w2,
                                             const float* __restrict__ b2,
                                             const float* __restrict__ w3,
                                             const float* __restrict__ b3,
                                             float* __restrict__ out) {
    __shared__ float gs[2 * HD];
    __shared__ float h1[HD];
    __shared__ float h2[64];
    int t = threadIdx.x;
    int g = blockIdx.x;
    gs[t] = gfeat[g * (2 * HD) + t];
    gs[HD + t] = gfeat[g * (2 * HD) + HD + t];
    __syncthreads();
    float a1 = b1[t];
    for (int k = 0; k < 2 * HD; k++) a1 += gs[k] * w1[k * HD + t];
    h1[t] = fmaxf(a1, 0.0f);
    __syncthreads();
    if (t < 64) {
        float a2 = b2[t];
        for (int k = 0; k < HD; k++) a2 += h1[k] * w2[k * 64 + t];
        h2[t] = fmaxf(a2, 0.0f);
    }
    __syncthreads();
    if (t == 0) {
        float a3 = b3[0];
        for (int k = 0; k < 64; k++) a3 += h2[k] * w3[k];
        out[g] = a3;
    }
}

extern "C" void kernel_launch(void* const* d_in, const int* in_sizes, int n_in,
                              void* d_out, int out_size, void* d_ws, size_t ws_size,
                              hipStream_t stream) {
    const float* x      = (const float*)d_in[0];
    const int*   eidx   = (const int*)d_in[1];   // [2, NE]: src then dst
    const int*   batch  = (const int*)d_in[2];
    const float* emb_W  = (const float*)d_in[3];
    const float* emb_b  = (const float*)d_in[4];
    const float* conv_W = (const float*)d_in[5]; // [3,128,128]
    const float* conv_b = (const float*)d_in[6]; // [3,128]
    const float* gamma  = (const float*)d_in[7];
    const float* beta   = (const float*)d_in[8];
    const float* w1     = (const float*)d_in[9];
    const float* b1     = (const float*)d_in[10];
    const float* w2     = (const float*)d_in[11];
    const float* b2     = (const float*)d_in[12];
    const float* w3     = (const float*)d_in[13];
    const float* b3     = (const float*)d_in[14];
    float* out = (float*)d_out;

    const int* src = eidx;
    const int* dst = eidx + NE;

    // workspace carve-up (floats)
    float* ws    = (float*)d_ws;
    float* A     = ws;                  // [NN*HD] node features (h)
    float* B     = A + NN * HD;         // [NN*HD] hw = h @ conv_W
    float* dinv  = B + NN * HD;         // [NN]
    float* bnsum = dinv + NN;           // [256] sum | sumsq
    float* bnss  = bnsum + 256;         // [256] scale | shift
    float* psum  = bnss + 256;          // [NG*HD]
    float* pmax  = psum + NG * HD;      // [NG*HD]
    float* cnt   = pmax + NG * HD;      // [NG]
    // total ~27.8M floats (~111 MB)

    // degree -> dinv
    hipMemsetAsync(dinv, 0, NN * sizeof(float), stream);
    k_deg<<<(NE + 255) / 256, 256, 0, stream>>>(dst, dinv);
    k_dinv<<<(NN + 255) / 256, 256, 0, stream>>>(dinv);

    // embedding
    k_emb<<<(NN + 7) / 8, 128, 0, stream>>>(x, emb_W, emb_b, A);

    const int NHBLK = (NN * HD + 255) / 256;
    for (int l = 0; l < NL; l++) {
        k_conv<<<(NN + 7) / 8, 128, 0, stream>>>(A, conv_W + l * HD * HD, B);
        k_scatter_init<<<NHBLK, 256, 0, stream>>>(B, dinv, conv_b + l * HD, A);
        k_edge<<<(NE * HD + 255) / 256, 256, 0, stream>>>(src, dst, dinv, B, A);
        hipMemsetAsync(bnsum, 0, 256 * sizeof(float), stream);
        k_bn_stats<<<256, 128, 0, stream>>>(A, bnsum);
        k_bn_fin<<<1, 128, 0, stream>>>(bnsum, gamma + l * HD, beta + l * HD, bnss);
        k_bn_apply<<<NHBLK, 256, 0, stream>>>(A, bnss);
    }

    // pooling (psum, pmax, cnt are contiguous -> one memset)
    hipMemsetAsync(psum, 0, (2 * NG * HD + NG) * sizeof(float), stream);
    k_pool<<<NHBLK, 256, 0, stream>>>(A, batch, psum, pmax);
    k_cnt<<<(NN + 255) / 256, 256, 0, stream>>>(batch, cnt);
    // reuse B's space for gfeat [NG, 256]
    float* gfeat = B;
    k_pool_fin<<<(NG * HD + 255) / 256, 256, 0, stream>>>(psum, pmax, cnt, gfeat);

    k_mlp<<<NG, 128, 0, stream>>>(gfeat, w1, b1, w2, b2, w3, b3, out);
}

// Round 2
// 1270.000 us; speedup vs baseline: 1.3390x; 1.3390x over previous
//
#include <hip/hip_runtime.h>

#define NN 100000   // nodes
#define NE 600000   // edges
#define NG 4096     // graphs
#define FIN 74
#define HD 128
#define NL 3
#define BN_EPS 1e-5f

// ---------------- CSR build ----------------
__global__ __launch_bounds__(256) void k_hist(const int* __restrict__ dst,
                                              int* __restrict__ degi) {
    int e = blockIdx.x * 256 + threadIdx.x;
    if (e < NE) atomicAdd(&degi[dst[e]], 1);
}

__global__ __launch_bounds__(256) void k_dinv(const int* __restrict__ degi,
                                              float* __restrict__ dinv) {
    int n = blockIdx.x * 256 + threadIdx.x;
    if (n < NN) dinv[n] = rsqrtf((float)degi[n] + 1.0f);  // +1 self-loop
}

// single-block exclusive scan over NN degree counts -> rowptr
__global__ __launch_bounds__(1024) void k_scan(const int* __restrict__ degi,
                                               int* __restrict__ rowptr) {
    __shared__ int part[1024];
    int t = threadIdx.x;
    const int CH = (NN + 1023) / 1024;  // 98
    int base = t * CH;
    int s = 0;
    for (int i = 0; i < CH; i++) {
        int idx = base + i;
        if (idx < NN) s += degi[idx];
    }
    part[t] = s;
    __syncthreads();
    for (int off = 1; off < 1024; off <<= 1) {
        int v = part[t];
        int add = (t >= off) ? part[t - off] : 0;
        __syncthreads();
        part[t] = v + add;
        __syncthreads();
    }
    int prefix = (t > 0) ? part[t - 1] : 0;
    for (int i = 0; i < CH; i++) {
        int idx = base + i;
        if (idx < NN) {
            rowptr[idx] = prefix;
            prefix += degi[idx];
        }
    }
    if (t == 1023) rowptr[NN] = prefix;  // == NE
}

__global__ __launch_bounds__(256) void k_fill(const int* __restrict__ src,
                                              const int* __restrict__ dst,
                                              const int* __restrict__ rowptr,
                                              int* __restrict__ cursor,
                                              int* __restrict__ col) {
    int e = blockIdx.x * 256 + threadIdx.x;
    if (e >= NE) return;
    int d = dst[e];
    int pos = rowptr[d] + atomicAdd(&cursor[d], 1);
    col[pos] = src[e];
}

// ---------------- embedding GEMM: h = relu(x @ W + b), K=74 ----------------
__global__ __launch_bounds__(128) void k_emb(const float* __restrict__ x,
                                             const float* __restrict__ W,
                                             const float* __restrict__ b,
                                             float* __restrict__ h) {
    __shared__ float xs[8][FIN];
    int c = threadIdx.x;
    int n0 = blockIdx.x * 8;
    for (int idx = c; idx < 8 * FIN; idx += 128) {
        int j = idx / FIN, k = idx % FIN;
        int n = n0 + j;
        xs[j][k] = (n < NN) ? x[n * FIN + k] : 0.0f;
    }
    __syncthreads();
    float bias = b[c];
    float acc[8];
#pragma unroll
    for (int j = 0; j < 8; j++) acc[j] = bias;
    for (int k = 0; k < FIN; k++) {
        float w = W[k * HD + c];
#pragma unroll
        for (int j = 0; j < 8; j++) acc[j] += xs[j][k] * w;
    }
#pragma unroll
    for (int j = 0; j < 8; j++) {
        int n = n0 + j;
        if (n < NN) h[n * HD + c] = fmaxf(acc[j], 0.0f);
    }
}

// ---------------- conv GEMM: hw = act(h) @ W, K=128 ----------------
// BN=true: act(v) = relu(v*ss[c] + ss[HD+c])  (fused BN of the previous layer)
template <bool BN>
__global__ __launch_bounds__(128) void k_conv(const float* __restrict__ hin,
                                              const float* __restrict__ ss,
                                              const float* __restrict__ W,
                                              float* __restrict__ hw) {
    __shared__ float hs[8][HD];
    int c = threadIdx.x;
    int n0 = blockIdx.x * 8;
    float sc = BN ? ss[c] : 1.0f;
    float sh = BN ? ss[HD + c] : 0.0f;
#pragma unroll
    for (int j = 0; j < 8; j++) {
        int n = n0 + j;
        float v = (n < NN) ? hin[n * HD + c] : 0.0f;
        if (BN) v = fmaxf(v * sc + sh, 0.0f);
        hs[j][c] = v;
    }
    __syncthreads();
    float acc[8] = {0.f, 0.f, 0.f, 0.f, 0.f, 0.f, 0.f, 0.f};
    for (int k = 0; k < HD; k++) {
        float w = W[k * HD + c];
#pragma unroll
        for (int j = 0; j < 8; j++) acc[j] += hs[j][k] * w;
    }
#pragma unroll
    for (int j = 0; j < 8; j++) {
        int n = n0 + j;
        if (n < NN) hw[n * HD + c] = acc[j];
    }
}

// ---------------- CSR gather: A[n] = sum_in hw[s]*dinv[s]*dinv[n] + hw[n]*dinv[n]^2 + bias
__global__ __launch_bounds__(128) void k_gather(const int* __restrict__ rowptr,
                                                const int* __restrict__ col,
                                                const float* __restrict__ dinv,
                                                const float* __restrict__ B,
                                                const float* __restrict__ bias,
                                                float* __restrict__ A) {
    int n = blockIdx.x;
    int c = threadIdx.x;
    float dd = dinv[n];
    float acc = B[n * HD + c] * dd * dd + bias[c];
    int j0 = rowptr[n], j1 = rowptr[n + 1];
    for (int j = j0; j < j1; j++) {
        int s = col[j];
        float nm = dinv[s] * dd;
        acc += B[s * HD + c] * nm;
    }
    A[n * HD + c] = acc;
}

// ---------------- BN statistics ----------------
__global__ __launch_bounds__(128) void k_bn_stats(const float* __restrict__ h,
                                                  float* __restrict__ sums) {
    int c = threadIdx.x;
    int chunk = (NN + gridDim.x - 1) / gridDim.x;
    int n0 = blockIdx.x * chunk;
    int n1 = min(n0 + chunk, NN);
    float s = 0.f, sq = 0.f;
    for (int n = n0; n < n1; n++) {
        float v = h[n * HD + c];
        s += v;
        sq += v * v;
    }
    atomicAdd(&sums[c], s);
    atomicAdd(&sums[HD + c], sq);
}

__global__ __launch_bounds__(128) void k_bn_fin(const float* __restrict__ sums,
                                                const float* __restrict__ gamma,
                                                const float* __restrict__ beta,
                                                float* __restrict__ ss) {
    int c = threadIdx.x;
    float inv_n = 1.0f / (float)NN;
    float mu = sums[c] * inv_n;
    float var = sums[HD + c] * inv_n - mu * mu;
    float sc = gamma[c] * rsqrtf(var + BN_EPS);
    ss[c] = sc;
    ss[HD + c] = beta[c] - mu * sc;
}

// ---------------- pooling (BN of last layer fused into the read) ----------------
__global__ __launch_bounds__(256) void k_pool(const float* __restrict__ h,
                                              const float* __restrict__ ss,
                                              const int* __restrict__ batch,
                                              float* __restrict__ psum,
                                              float* __restrict__ pmax) {
    int idx = blockIdx.x * 256 + threadIdx.x;
    if (idx >= NN * HD) return;
    int n = idx >> 7;
    int c = idx & 127;
    int g = batch[n];
    float v = fmaxf(h[idx] * ss[c] + ss[HD + c], 0.0f);
    atomicAdd(&psum[g * HD + c], v);
    // v >= 0: uint bit order == float order; 0-init matches empty-segment guard
    atomicMax((unsigned int*)&pmax[g * HD + c], __float_as_uint(v));
}

__global__ __launch_bounds__(256) void k_cnt(const int* __restrict__ batch,
                                             float* __restrict__ cnt) {
    int n = blockIdx.x * 256 + threadIdx.x;
    if (n < NN) atomicAdd(&cnt[batch[n]], 1.0f);
}

__global__ __launch_bounds__(256) void k_pool_fin(const float* __restrict__ psum,
                                                  const float* __restrict__ pmax,
                                                  const float* __restrict__ cnt,
                                                  float* __restrict__ gfeat) {
    int idx = blockIdx.x * 256 + threadIdx.x;
    if (idx >= NG * HD) return;
    int g = idx >> 7;
    int c = idx & 127;
    float ct = fmaxf(cnt[g], 1.0f);
    gfeat[g * (2 * HD) + c] = psum[idx] / ct;
    gfeat[g * (2 * HD) + HD + c] = pmax[idx];
}

// ---------------- fused MLP head ----------------
__global__ __launch_bounds__(128) void k_mlp(const float* __restrict__ gfeat,
                                             const float* __restrict__ w1,
                                             const float* __restrict__ b1,
                                             const float* __restrict__ w2,
                                             const float* __restrict__ b2,
                                             const float* __restrict__ w3,
                                             const float* __restrict__ b3,
                                             float* __restrict__ out) {
    __shared__ float gs[2 * HD];
    __shared__ float h1[HD];
    __shared__ float h2[64];
    int t = threadIdx.x;
    int g = blockIdx.x;
    gs[t] = gfeat[g * (2 * HD) + t];
    gs[HD + t] = gfeat[g * (2 * HD) + HD + t];
    __syncthreads();
    float a1 = b1[t];
    for (int k = 0; k < 2 * HD; k++) a1 += gs[k] * w1[k * HD + t];
    h1[t] = fmaxf(a1, 0.0f);
    __syncthreads();
    if (t < 64) {
        float a2 = b2[t];
        for (int k = 0; k < HD; k++) a2 += h1[k] * w2[k * 64 + t];
        h2[t] = fmaxf(a2, 0.0f);
    }
    __syncthreads();
    if (t == 0) {
        float a3 = b3[0];
        for (int k = 0; k < 64; k++) a3 += h2[k] * w3[k];
        out[g] = a3;
    }
}

extern "C" void kernel_launch(void* const* d_in, const int* in_sizes, int n_in,
                              void* d_out, int out_size, void* d_ws, size_t ws_size,
                              hipStream_t stream) {
    const float* x      = (const float*)d_in[0];
    const int*   eidx   = (const int*)d_in[1];   // [2, NE]: src then dst
    const int*   batch  = (const int*)d_in[2];
    const float* emb_W  = (const float*)d_in[3];
    const float* emb_b  = (const float*)d_in[4];
    const float* conv_W = (const float*)d_in[5]; // [3,128,128]
    const float* conv_b = (const float*)d_in[6]; // [3,128]
    const float* gamma  = (const float*)d_in[7];
    const float* beta   = (const float*)d_in[8];
    const float* w1     = (const float*)d_in[9];
    const float* b1     = (const float*)d_in[10];
    const float* w2     = (const float*)d_in[11];
    const float* b2     = (const float*)d_in[12];
    const float* w3     = (const float*)d_in[13];
    const float* b3     = (const float*)d_in[14];
    float* out = (float*)d_out;

    const int* src = eidx;
    const int* dst = eidx + NE;

    // workspace carve-up
    float* ws    = (float*)d_ws;
    float* A     = ws;                  // [NN*HD] node features
    float* B     = A + NN * HD;         // [NN*HD] hw
    float* dinv  = B + NN * HD;         // [NN]
    float* bnsum = dinv + NN;           // [256]
    float* bnss  = bnsum + 256;         // [256]
    float* psum  = bnss + 256;          // [NG*HD]
    float* pmax  = psum + NG * HD;      // [NG*HD]
    float* cnt   = pmax + NG * HD;      // [NG]
    int*   degi  = (int*)(cnt + NG);    // [NN]
    int*   rowptr= degi + NN;           // [NN+1]
    int*   cursor= rowptr + NN + 1;     // [NN]
    int*   col   = cursor + NN;         // [NE]
    // total ~27.1M elems (~108 MB)

    // ---- CSR build + dinv ----
    hipMemsetAsync(degi, 0, (2 * NN + 1 + NN) * sizeof(int), stream); // degi,rowptr,cursor
    k_hist<<<(NE + 255) / 256, 256, 0, stream>>>(dst, degi);
    k_dinv<<<(NN + 255) / 256, 256, 0, stream>>>(degi, dinv);
    k_scan<<<1, 1024, 0, stream>>>(degi, rowptr);
    k_fill<<<(NE + 255) / 256, 256, 0, stream>>>(src, dst, rowptr, cursor, col);

    // ---- embedding ----
    k_emb<<<(NN + 7) / 8, 128, 0, stream>>>(x, emb_W, emb_b, A);

    for (int l = 0; l < NL; l++) {
        if (l == 0)
            k_conv<false><<<(NN + 7) / 8, 128, 0, stream>>>(A, nullptr, conv_W, B);
        else
            k_conv<true><<<(NN + 7) / 8, 128, 0, stream>>>(A, bnss, conv_W + l * HD * HD, B);
        k_gather<<<NN, 128, 0, stream>>>(rowptr, col, dinv, B, conv_b + l * HD, A);
        hipMemsetAsync(bnsum, 0, 256 * sizeof(float), stream);
        k_bn_stats<<<256, 128, 0, stream>>>(A, bnsum);
        k_bn_fin<<<1, 128, 0, stream>>>(bnsum, gamma + l * HD, beta + l * HD, bnss);
    }

    // ---- pooling (BN of layer 2 fused) ----
    hipMemsetAsync(psum, 0, (2 * NG * HD + NG) * sizeof(float), stream);
    const int NHBLK = (NN * HD + 255) / 256;
    k_pool<<<NHBLK, 256, 0, stream>>>(A, bnss, batch, psum, pmax);
    k_cnt<<<(NN + 255) / 256, 256, 0, stream>>>(batch, cnt);
    float* gfeat = B;  // reuse
    k_pool_fin<<<(NG * HD + 255) / 256, 256, 0, stream>>>(psum, pmax, cnt, gfeat);

    k_mlp<<<NG, 128, 0, stream>>>(gfeat, w1, b1, w2, b2, w3, b3, out);
}

// Round 3
// 842.096 us; speedup vs baseline: 2.0194x; 1.5081x over previous
//
#include <hip/hip_runtime.h>

#define NN 100000   // nodes
#define NE 600000   // edges
#define NG 4096     // graphs
#define FIN 74
#define HD 128
#define NL 3
#define BN_EPS 1e-5f
#define NSCAN 391   // ceil(NN/256)

typedef __attribute__((ext_vector_type(8))) short short8;
typedef __attribute__((ext_vector_type(4))) float floatx4;

__device__ __forceinline__ unsigned short f2bf(float f) {
    unsigned u = __float_as_uint(f);
    u += 0x7fff + ((u >> 16) & 1);   // round-to-nearest-even
    return (unsigned short)(u >> 16);
}

// ---------------- CSR build ----------------
__global__ __launch_bounds__(256) void k_hist(const int* __restrict__ dst,
                                              int* __restrict__ degi) {
    int e = blockIdx.x * 256 + threadIdx.x;
    if (e < NE) atomicAdd(&degi[dst[e]], 1);
}

__global__ __launch_bounds__(256) void k_dinv(const int* __restrict__ degi,
                                              float* __restrict__ dinv) {
    int n = blockIdx.x * 256 + threadIdx.x;
    if (n < NN) dinv[n] = rsqrtf((float)degi[n] + 1.0f);  // +1 self-loop
}

// hierarchical scan: block sums -> scan partials -> per-block exclusive
__global__ __launch_bounds__(256) void k_scan1(const int* __restrict__ degi,
                                               int* __restrict__ part) {
    __shared__ int s[256];
    int t = threadIdx.x;
    int idx = blockIdx.x * 256 + t;
    s[t] = (idx < NN) ? degi[idx] : 0;
    __syncthreads();
    for (int off = 128; off > 0; off >>= 1) {
        if (t < off) s[t] += s[t + off];
        __syncthreads();
    }
    if (t == 0) part[blockIdx.x] = s[0];
}

__global__ __launch_bounds__(512) void k_scan2(int* __restrict__ part) {
    __shared__ int s[512];
    int t = threadIdx.x;
    s[t] = (t < NSCAN) ? part[t] : 0;
    __syncthreads();
    for (int off = 1; off < 512; off <<= 1) {
        int v = s[t];
        int a = (t >= off) ? s[t - off] : 0;
        __syncthreads();
        s[t] = v + a;
        __syncthreads();
    }
    if (t < NSCAN) part[t] = (t > 0) ? s[t - 1] : 0;  // exclusive
}

__global__ __launch_bounds__(256) void k_scan3(const int* __restrict__ degi,
                                               const int* __restrict__ part,
                                               int* __restrict__ rowptr) {
    __shared__ int s[256];
    int t = threadIdx.x;
    int idx = blockIdx.x * 256 + t;
    int v = (idx < NN) ? degi[idx] : 0;
    s[t] = v;
    __syncthreads();
    for (int off = 1; off < 256; off <<= 1) {
        int x = s[t];
        int a = (t >= off) ? s[t - off] : 0;
        __syncthreads();
        s[t] = x + a;
        __syncthreads();
    }
    if (idx < NN) rowptr[idx] = part[blockIdx.x] + (s[t] - v);
    if (idx == 0) rowptr[NN] = NE;
}

__global__ __launch_bounds__(256) void k_fill(const int* __restrict__ src,
                                              const int* __restrict__ dst,
                                              const int* __restrict__ rowptr,
                                              int* __restrict__ cursor,
                                              int* __restrict__ col) {
    int e = blockIdx.x * 256 + threadIdx.x;
    if (e >= NE) return;
    int d = dst[e];
    int pos = rowptr[d] + atomicAdd(&cursor[d], 1);
    col[pos] = src[e];
}

// ---------------- weight fragment pre-pack (bf16) ----------------
// conv: Wf[l][nt][kstep][g][n][j], nt=0..7, kstep=0..3, g=0..3, n=0..15, j=0..7
__global__ __launch_bounds__(256) void k_wconv(const float* __restrict__ W,
                                               unsigned short* __restrict__ Wf) {
    int d = blockIdx.x * 256 + threadIdx.x;
    if (d >= NL * 16384) return;
    int layer = d >> 14, r = d & 16383;
    int j = r & 7, n = (r >> 3) & 15, g = (r >> 7) & 3, kstep = (r >> 9) & 3, nt = r >> 11;
    int k = kstep * 32 + g * 8 + j;
    Wf[d] = f2bf(W[layer * 16384 + k * HD + nt * 16 + n]);
}

// emb: K padded 74 -> 96 (3 ksteps)
__global__ __launch_bounds__(256) void k_wemb(const float* __restrict__ W,
                                              unsigned short* __restrict__ Wf) {
    int d = blockIdx.x * 256 + threadIdx.x;
    if (d >= 12288) return;
    int inner = d & 511, outer = d >> 9;
    int kstep = outer % 3, nt = outer / 3;
    int g = inner >> 7, n = (inner >> 3) & 15, j = inner & 7;
    int k = kstep * 32 + g * 8 + j;
    float v = (k < FIN) ? W[k * HD + nt * 16 + n] : 0.0f;
    Wf[d] = f2bf(v);
}

// ---------------- embedding MFMA: h = relu(x @ W + b), K=74 pad 96 ----------------
__global__ __launch_bounds__(256) void k_emb(const float* __restrict__ x,
                                             const unsigned short* __restrict__ Wf,
                                             const float* __restrict__ b,
                                             float* __restrict__ h) {
    __shared__ __align__(16) unsigned short As[3072];  // 32 nodes x 96 k, frag order
    int t = threadIdx.x;
    int n0 = blockIdx.x * 32;
    for (int f = t; f < 3072; f += 256) {
        int m = f / 96, kp = f % 96;
        float v = (kp < FIN) ? x[(n0 + m) * FIN + kp] : 0.0f;
        int kstep = kp >> 5, g = (kp >> 3) & 3, j = kp & 7;
        As[((kstep * 4 + g) * 32 + m) * 8 + j] = f2bf(v);
    }
    __syncthreads();
    int lane = t & 63, wv = t >> 6;
    int lanelo = lane & 15, g = lane >> 4;
    floatx4 acc[2][2] = {};
#pragma unroll
    for (int kstep = 0; kstep < 3; kstep++) {
        short8 a0 = *(const short8*)&As[((kstep * 4 + g) * 32 + lanelo) * 8];
        short8 a1 = *(const short8*)&As[((kstep * 4 + g) * 32 + 16 + lanelo) * 8];
        short8 b0 = *(const short8*)&Wf[(((wv * 2 + 0) * 3 + kstep) * 4 + g) * 128 + lanelo * 8];
        short8 b1 = *(const short8*)&Wf[(((wv * 2 + 1) * 3 + kstep) * 4 + g) * 128 + lanelo * 8];
        acc[0][0] = __builtin_amdgcn_mfma_f32_16x16x32_bf16(a0, b0, acc[0][0], 0, 0, 0);
        acc[0][1] = __builtin_amdgcn_mfma_f32_16x16x32_bf16(a0, b1, acc[0][1], 0, 0, 0);
        acc[1][0] = __builtin_amdgcn_mfma_f32_16x16x32_bf16(a1, b0, acc[1][0], 0, 0, 0);
        acc[1][1] = __builtin_amdgcn_mfma_f32_16x16x32_bf16(a1, b1, acc[1][1], 0, 0, 0);
    }
#pragma unroll
    for (int ns = 0; ns < 2; ns++) {
        int colc = wv * 32 + ns * 16 + lanelo;
        float bias = b[colc];
#pragma unroll
        for (int ms = 0; ms < 2; ms++)
#pragma unroll
            for (int r = 0; r < 4; r++) {
                int row = n0 + ms * 16 + g * 4 + r;
                h[row * HD + colc] = fmaxf(acc[ms][ns][r] + bias, 0.0f);
            }
    }
}

// ---------------- conv MFMA: hw = act(h) @ W, K=128 ----------------
// BN=true: act(v) = relu(v*ss[k] + ss[128+k]) fused into the bf16 cast
template <bool BN>
__global__ __launch_bounds__(256) void k_conv(const float* __restrict__ hin,
                                              const float* __restrict__ ss,
                                              const unsigned short* __restrict__ Wf,
                                              float* __restrict__ hw) {
    __shared__ __align__(16) unsigned short As[4096];  // 32 nodes x 128 k, frag order
    int t = threadIdx.x;
    int n0 = blockIdx.x * 32;
    int f0 = t * 4;
    int k0 = f0 & 127;                 // constant across i (stride 1024)
    floatx4 scv = {1.f, 1.f, 1.f, 1.f}, shv = {0.f, 0.f, 0.f, 0.f};
    if (BN) {
        scv = *(const floatx4*)&ss[k0];
        shv = *(const floatx4*)&ss[HD + k0];
    }
    int kstep = k0 >> 5, g0 = (k0 >> 3) & 3, j0 = k0 & 7;
    int lbase = (kstep * 4 + g0) * 256 + j0;  // halfword idx sans m*8
#pragma unroll
    for (int i = 0; i < 4; i++) {
        int f = f0 + i * 1024;
        int m = f >> 7;
        floatx4 v = *(const floatx4*)&hin[n0 * HD + f];
        if (BN) {
            v = v * scv + shv;
            v.x = fmaxf(v.x, 0.f); v.y = fmaxf(v.y, 0.f);
            v.z = fmaxf(v.z, 0.f); v.w = fmaxf(v.w, 0.f);
        }
        unsigned long long pack = (unsigned long long)f2bf(v.x)
                                | ((unsigned long long)f2bf(v.y) << 16)
                                | ((unsigned long long)f2bf(v.z) << 32)
                                | ((unsigned long long)f2bf(v.w) << 48);
        *(unsigned long long*)&As[lbase + m * 8] = pack;
    }
    __syncthreads();
    int lane = t & 63, wv = t >> 6;
    int lanelo = lane & 15, g = lane >> 4;
    floatx4 acc[2][2] = {};
#pragma unroll
    for (int ks = 0; ks < 4; ks++) {
        short8 a0 = *(const short8*)&As[((ks * 4 + g) * 32 + lanelo) * 8];
        short8 a1 = *(const short8*)&As[((ks * 4 + g) * 32 + 16 + lanelo) * 8];
        short8 b0 = *(const short8*)&Wf[(((wv * 2 + 0) * 4 + ks) * 4 + g) * 128 + lanelo * 8];
        short8 b1 = *(const short8*)&Wf[(((wv * 2 + 1) * 4 + ks) * 4 + g) * 128 + lanelo * 8];
        acc[0][0] = __builtin_amdgcn_mfma_f32_16x16x32_bf16(a0, b0, acc[0][0], 0, 0, 0);
        acc[0][1] = __builtin_amdgcn_mfma_f32_16x16x32_bf16(a0, b1, acc[0][1], 0, 0, 0);
        acc[1][0] = __builtin_amdgcn_mfma_f32_16x16x32_bf16(a1, b0, acc[1][0], 0, 0, 0);
        acc[1][1] = __builtin_amdgcn_mfma_f32_16x16x32_bf16(a1, b1, acc[1][1], 0, 0, 0);
    }
#pragma unroll
    for (int ms = 0; ms < 2; ms++)
#pragma unroll
        for (int ns = 0; ns < 2; ns++) {
            int colc = wv * 32 + ns * 16 + lanelo;
#pragma unroll
            for (int r = 0; r < 4; r++) {
                int row = n0 + ms * 16 + g * 4 + r;
                hw[row * HD + colc] = acc[ms][ns][r];
            }
        }
}

// ---------------- CSR gather: A[n] = sum_in B[s]*dinv[s]*dinv[n] + B[n]*dinv[n]^2 + bias
__global__ __launch_bounds__(128) void k_gather(const int* __restrict__ rowptr,
                                                const int* __restrict__ col,
                                                const float* __restrict__ dinv,
                                                const float* __restrict__ B,
                                                const float* __restrict__ bias,
                                                float* __restrict__ A) {
    int t = threadIdx.x;
    int n = blockIdx.x * 4 + (t >> 5);   // 4 nodes/block
    int c4 = (t & 31) * 4;
    float dd = dinv[n];
    floatx4 acc = *(const floatx4*)&B[n * HD + c4];
    acc = acc * (dd * dd) + *(const floatx4*)&bias[c4];
    int j0 = rowptr[n], j1 = rowptr[n + 1];
    for (int j = j0; j < j1; j++) {
        int s = col[j];
        float nm = dinv[s] * dd;
        floatx4 v = *(const floatx4*)&B[s * HD + c4];
        acc += v * nm;
    }
    *(floatx4*)&A[n * HD + c4] = acc;
}

// ---------------- BN statistics ----------------
__global__ __launch_bounds__(128) void k_bn_stats(const float* __restrict__ h,
                                                  float* __restrict__ sums) {
    int c = threadIdx.x;
    int chunk = (NN + gridDim.x - 1) / gridDim.x;
    int n0 = blockIdx.x * chunk;
    int n1 = min(n0 + chunk, NN);
    float s = 0.f, sq = 0.f;
    for (int n = n0; n < n1; n++) {
        float v = h[n * HD + c];
        s += v;
        sq += v * v;
    }
    atomicAdd(&sums[c], s);
    atomicAdd(&sums[HD + c], sq);
}

__global__ __launch_bounds__(128) void k_bn_fin(const float* __restrict__ sums,
                                                const float* __restrict__ gamma,
                                                const float* __restrict__ beta,
                                                float* __restrict__ ss) {
    int c = threadIdx.x;
    float inv_n = 1.0f / (float)NN;
    float mu = sums[c] * inv_n;
    float var = sums[HD + c] * inv_n - mu * mu;
    float sc = gamma[c] * rsqrtf(var + BN_EPS);
    ss[c] = sc;
    ss[HD + c] = beta[c] - mu * sc;
}

// ---------------- pooling (BN of last layer fused into the read) ----------------
__global__ __launch_bounds__(256) void k_pool(const float* __restrict__ h,
                                              const float* __restrict__ ss,
                                              const int* __restrict__ batch,
                                              float* __restrict__ psum,
                                              float* __restrict__ pmax) {
    int idx = blockIdx.x * 256 + threadIdx.x;
    if (idx >= NN * HD) return;
    int n = idx >> 7;
    int c = idx & 127;
    int g = batch[n];
    float v = fmaxf(h[idx] * ss[c] + ss[HD + c], 0.0f);
    atomicAdd(&psum[g * HD + c], v);
    atomicMax((unsigned int*)&pmax[g * HD + c], __float_as_uint(v));
}

__global__ __launch_bounds__(256) void k_cnt(const int* __restrict__ batch,
                                             float* __restrict__ cnt) {
    int n = blockIdx.x * 256 + threadIdx.x;
    if (n < NN) atomicAdd(&cnt[batch[n]], 1.0f);
}

__global__ __launch_bounds__(256) void k_pool_fin(const float* __restrict__ psum,
                                                  const float* __restrict__ pmax,
                                                  const float* __restrict__ cnt,
                                                  float* __restrict__ gfeat) {
    int idx = blockIdx.x * 256 + threadIdx.x;
    if (idx >= NG * HD) return;
    int g = idx >> 7;
    int c = idx & 127;
    float ct = fmaxf(cnt[g], 1.0f);
    gfeat[g * (2 * HD) + c] = psum[idx] / ct;
    gfeat[g * (2 * HD) + HD + c] = pmax[idx];
}

// ---------------- fused MLP head ----------------
__global__ __launch_bounds__(128) void k_mlp(const float* __restrict__ gfeat,
                                             const float* __restrict__ w1,
                                             const float* __restrict__ b1,
                                             const float* __restrict__ w2,
                                             const float* __restrict__ b2,
                                             const float* __restrict__ w3,
                                             const float* __restrict__ b3,
                                             float* __restrict__ out) {
    __shared__ float gs[2 * HD];
    __shared__ float h1[HD];
    __shared__ float h2[64];
    int t = threadIdx.x;
    int g = blockIdx.x;
    gs[t] = gfeat[g * (2 * HD) + t];
    gs[HD + t] = gfeat[g * (2 * HD) + HD + t];
    __syncthreads();
    float a1 = b1[t];
    for (int k = 0; k < 2 * HD; k++) a1 += gs[k] * w1[k * HD + t];
    h1[t] = fmaxf(a1, 0.0f);
    __syncthreads();
    if (t < 64) {
        float a2 = b2[t];
        for (int k = 0; k < HD; k++) a2 += h1[k] * w2[k * 64 + t];
        h2[t] = fmaxf(a2, 0.0f);
    }
    __syncthreads();
    if (t == 0) {
        float a3 = b3[0];
        for (int k = 0; k < 64; k++) a3 += h2[k] * w3[k];
        out[g] = a3;
    }
}

extern "C" void kernel_launch(void* const* d_in, const int* in_sizes, int n_in,
                              void* d_out, int out_size, void* d_ws, size_t ws_size,
                              hipStream_t stream) {
    const float* x      = (const float*)d_in[0];
    const int*   eidx   = (const int*)d_in[1];   // [2, NE]: src then dst
    const int*   batch  = (const int*)d_in[2];
    const float* emb_W  = (const float*)d_in[3];
    const float* emb_b  = (const float*)d_in[4];
    const float* conv_W = (const float*)d_in[5]; // [3,128,128]
    const float* conv_b = (const float*)d_in[6]; // [3,128]
    const float* gamma  = (const float*)d_in[7];
    const float* beta   = (const float*)d_in[8];
    const float* w1     = (const float*)d_in[9];
    const float* b1     = (const float*)d_in[10];
    const float* w2     = (const float*)d_in[11];
    const float* b2     = (const float*)d_in[12];
    const float* w3     = (const float*)d_in[13];
    const float* b3     = (const float*)d_in[14];
    float* out = (float*)d_out;

    const int* src = eidx;
    const int* dst = eidx + NE;

    // workspace carve-up
    float* ws    = (float*)d_ws;
    float* A     = ws;                  // [NN*HD]
    float* B     = A + NN * HD;         // [NN*HD]
    float* dinv  = B + NN * HD;         // [NN]
    float* bnsum = dinv + NN;           // [256]
    float* bnss  = bnsum + 256;         // [256]
    float* psum  = bnss + 256;          // [NG*HD]
    float* pmax  = psum + NG * HD;      // [NG*HD]
    float* cnt   = pmax + NG * HD;      // [NG]
    int*   degi  = (int*)(cnt + NG);    // [NN]
    int*   cursor= degi + NN;           // [NN]  (contiguous with degi for 1 memset)
    int*   rowptr= cursor + NN;         // [NN+1]
    int*   part  = rowptr + NN + 1;     // [NSCAN]
    int*   col   = part + NSCAN;        // [NE]
    unsigned short* WfE = (unsigned short*)(col + NE);  // [12288]
    unsigned short* WfC = WfE + 12288;                  // [3*16384]

    // ---- CSR build + dinv ----
    hipMemsetAsync(degi, 0, 2 * NN * sizeof(int), stream);  // degi + cursor
    k_hist<<<(NE + 255) / 256, 256, 0, stream>>>(dst, degi);
    k_dinv<<<(NN + 255) / 256, 256, 0, stream>>>(degi, dinv);
    k_scan1<<<NSCAN, 256, 0, stream>>>(degi, part);
    k_scan2<<<1, 512, 0, stream>>>(part);
    k_scan3<<<NSCAN, 256, 0, stream>>>(degi, part, rowptr);
    k_fill<<<(NE + 255) / 256, 256, 0, stream>>>(src, dst, rowptr, cursor, col);

    // ---- weight pre-pack ----
    k_wemb<<<(12288 + 255) / 256, 256, 0, stream>>>(emb_W, WfE);
    k_wconv<<<(NL * 16384 + 255) / 256, 256, 0, stream>>>(conv_W, WfC);

    // ---- embedding ----
    k_emb<<<NN / 32, 256, 0, stream>>>(x, WfE, emb_b, A);

    for (int l = 0; l < NL; l++) {
        if (l == 0)
            k_conv<false><<<NN / 32, 256, 0, stream>>>(A, nullptr, WfC, B);
        else
            k_conv<true><<<NN / 32, 256, 0, stream>>>(A, bnss, WfC + l * 16384, B);
        k_gather<<<NN / 4, 128, 0, stream>>>(rowptr, col, dinv, B, conv_b + l * HD, A);
        hipMemsetAsync(bnsum, 0, 256 * sizeof(float), stream);
        k_bn_stats<<<256, 128, 0, stream>>>(A, bnsum);
        k_bn_fin<<<1, 128, 0, stream>>>(bnsum, gamma + l * HD, beta + l * HD, bnss);
    }

    // ---- pooling (BN of layer 2 fused) ----
    hipMemsetAsync(psum, 0, (2 * NG * HD + NG) * sizeof(float), stream);
    const int NHBLK = (NN * HD + 255) / 256;
    k_pool<<<NHBLK, 256, 0, stream>>>(A, bnss, batch, psum, pmax);
    k_cnt<<<(NN + 255) / 256, 256, 0, stream>>>(batch, cnt);
    float* gfeat = B;  // reuse
    k_pool_fin<<<(NG * HD + 255) / 256, 256, 0, stream>>>(psum, pmax, cnt, gfeat);

    k_mlp<<<NG, 128, 0, stream>>>(gfeat, w1, b1, w2, b2, w3, b3, out);
}

// Round 4
// 551.102 us; speedup vs baseline: 3.0857x; 1.5280x over previous
//
#include <hip/hip_runtime.h>

#define NN 100000   // nodes
#define NE 600000   // edges
#define NG 4096     // graphs
#define FIN 74
#define HD 128
#define NL 3
#define BN_EPS 1e-5f
#define NSCAN 391   // ceil(NN/256)

typedef __attribute__((ext_vector_type(8))) short short8;
typedef __attribute__((ext_vector_type(4))) float floatx4;

__device__ __forceinline__ unsigned short f2bf(float f) {
    unsigned u = __float_as_uint(f);
    u += 0x7fff + ((u >> 16) & 1);   // round-to-nearest-even
    return (unsigned short)(u >> 16);
}

// ---------------- CSR build ----------------
__global__ __launch_bounds__(256) void k_hist(const int* __restrict__ dst,
                                              int* __restrict__ degi) {
    int e = blockIdx.x * 256 + threadIdx.x;
    if (e < NE) atomicAdd(&degi[dst[e]], 1);
}

__global__ __launch_bounds__(256) void k_dinv(const int* __restrict__ degi,
                                              float* __restrict__ dinv) {
    int n = blockIdx.x * 256 + threadIdx.x;
    if (n < NN) dinv[n] = rsqrtf((float)degi[n] + 1.0f);  // +1 self-loop
}

// hierarchical scan: block sums -> scan partials -> per-block exclusive
__global__ __launch_bounds__(256) void k_scan1(const int* __restrict__ degi,
                                               int* __restrict__ part) {
    __shared__ int s[256];
    int t = threadIdx.x;
    int idx = blockIdx.x * 256 + t;
    s[t] = (idx < NN) ? degi[idx] : 0;
    __syncthreads();
    for (int off = 128; off > 0; off >>= 1) {
        if (t < off) s[t] += s[t + off];
        __syncthreads();
    }
    if (t == 0) part[blockIdx.x] = s[0];
}

__global__ __launch_bounds__(512) void k_scan2(int* __restrict__ part) {
    __shared__ int s[512];
    int t = threadIdx.x;
    s[t] = (t < NSCAN) ? part[t] : 0;
    __syncthreads();
    for (int off = 1; off < 512; off <<= 1) {
        int v = s[t];
        int a = (t >= off) ? s[t - off] : 0;
        __syncthreads();
        s[t] = v + a;
        __syncthreads();
    }
    if (t < NSCAN) part[t] = (t > 0) ? s[t - 1] : 0;  // exclusive
}

__global__ __launch_bounds__(256) void k_scan3(const int* __restrict__ degi,
                                               const int* __restrict__ part,
                                               int* __restrict__ rowptr) {
    __shared__ int s[256];
    int t = threadIdx.x;
    int idx = blockIdx.x * 256 + t;
    int v = (idx < NN) ? degi[idx] : 0;
    s[t] = v;
    __syncthreads();
    for (int off = 1; off < 256; off <<= 1) {
        int x = s[t];
        int a = (t >= off) ? s[t - off] : 0;
        __syncthreads();
        s[t] = x + a;
        __syncthreads();
    }
    if (idx < NN) rowptr[idx] = part[blockIdx.x] + (s[t] - v);
    if (idx == 0) rowptr[NN] = NE;
}

__global__ __launch_bounds__(256) void k_fill(const int* __restrict__ src,
                                              const int* __restrict__ dst,
                                              const int* __restrict__ rowptr,
                                              int* __restrict__ cursor,
                                              int* __restrict__ col) {
    int e = blockIdx.x * 256 + threadIdx.x;
    if (e >= NE) return;
    int d = dst[e];
    int pos = rowptr[d] + atomicAdd(&cursor[d], 1);
    col[pos] = src[e];
}

// ---------------- graph boundaries from sorted batch ----------------
__global__ __launch_bounds__(256) void k_bounds(const int* __restrict__ batch,
                                                int* __restrict__ gstart) {
    int n = blockIdx.x * 256 + threadIdx.x;
    if (n >= NN) return;
    int b = batch[n];
    int bp = (n == 0) ? -1 : batch[n - 1];
    for (int g = bp + 1; g <= b; g++) gstart[g] = n;
    if (n == NN - 1)
        for (int g = b + 1; g <= NG; g++) gstart[g] = NN;
}

// ---------------- weight fragment pre-pack (bf16) ----------------
__global__ __launch_bounds__(256) void k_wconv(const float* __restrict__ W,
                                               unsigned short* __restrict__ Wf) {
    int d = blockIdx.x * 256 + threadIdx.x;
    if (d >= NL * 16384) return;
    int layer = d >> 14, r = d & 16383;
    int j = r & 7, n = (r >> 3) & 15, g = (r >> 7) & 3, kstep = (r >> 9) & 3, nt = r >> 11;
    int k = kstep * 32 + g * 8 + j;
    Wf[d] = f2bf(W[layer * 16384 + k * HD + nt * 16 + n]);
}

__global__ __launch_bounds__(256) void k_wemb(const float* __restrict__ W,
                                              unsigned short* __restrict__ Wf) {
    int d = blockIdx.x * 256 + threadIdx.x;
    if (d >= 12288) return;
    int inner = d & 511, outer = d >> 9;
    int kstep = outer % 3, nt = outer / 3;
    int g = inner >> 7, n = (inner >> 3) & 15, j = inner & 7;
    int k = kstep * 32 + g * 8 + j;
    float v = (k < FIN) ? W[k * HD + nt * 16 + n] : 0.0f;
    Wf[d] = f2bf(v);
}

// ---------------- embedding MFMA: h = relu(x @ W + b), K=74 pad 96 ----------------
__global__ __launch_bounds__(256) void k_emb(const float* __restrict__ x,
                                             const unsigned short* __restrict__ Wf,
                                             const float* __restrict__ b,
                                             float* __restrict__ h) {
    __shared__ __align__(16) unsigned short As[3072];  // 32 nodes x 96 k, frag order
    int t = threadIdx.x;
    int n0 = blockIdx.x * 32;
    for (int f = t; f < 3072; f += 256) {
        int m = f / 96, kp = f % 96;
        float v = (kp < FIN) ? x[(n0 + m) * FIN + kp] : 0.0f;
        int kstep = kp >> 5, g = (kp >> 3) & 3, j = kp & 7;
        As[((kstep * 4 + g) * 32 + m) * 8 + j] = f2bf(v);
    }
    __syncthreads();
    int lane = t & 63, wv = t >> 6;
    int lanelo = lane & 15, g = lane >> 4;
    floatx4 acc[2][2] = {};
#pragma unroll
    for (int kstep = 0; kstep < 3; kstep++) {
        short8 a0 = *(const short8*)&As[((kstep * 4 + g) * 32 + lanelo) * 8];
        short8 a1 = *(const short8*)&As[((kstep * 4 + g) * 32 + 16 + lanelo) * 8];
        short8 b0 = *(const short8*)&Wf[(((wv * 2 + 0) * 3 + kstep) * 4 + g) * 128 + lanelo * 8];
        short8 b1 = *(const short8*)&Wf[(((wv * 2 + 1) * 3 + kstep) * 4 + g) * 128 + lanelo * 8];
        acc[0][0] = __builtin_amdgcn_mfma_f32_16x16x32_bf16(a0, b0, acc[0][0], 0, 0, 0);
        acc[0][1] = __builtin_amdgcn_mfma_f32_16x16x32_bf16(a0, b1, acc[0][1], 0, 0, 0);
        acc[1][0] = __builtin_amdgcn_mfma_f32_16x16x32_bf16(a1, b0, acc[1][0], 0, 0, 0);
        acc[1][1] = __builtin_amdgcn_mfma_f32_16x16x32_bf16(a1, b1, acc[1][1], 0, 0, 0);
    }
#pragma unroll
    for (int ns = 0; ns < 2; ns++) {
        int colc = wv * 32 + ns * 16 + lanelo;
        float bias = b[colc];
#pragma unroll
        for (int ms = 0; ms < 2; ms++)
#pragma unroll
            for (int r = 0; r < 4; r++) {
                int row = n0 + ms * 16 + g * 4 + r;
                h[row * HD + colc] = fmaxf(acc[ms][ns][r] + bias, 0.0f);
            }
    }
}

// ---------------- conv MFMA: hw = act(h) @ W, K=128 ----------------
template <bool BN>
__global__ __launch_bounds__(256) void k_conv(const float* __restrict__ hin,
                                              const float* __restrict__ ss,
                                              const unsigned short* __restrict__ Wf,
                                              float* __restrict__ hw) {
    __shared__ __align__(16) unsigned short As[4096];  // 32 nodes x 128 k, frag order
    int t = threadIdx.x;
    int n0 = blockIdx.x * 32;
    int f0 = t * 4;
    int k0 = f0 & 127;
    floatx4 scv = {1.f, 1.f, 1.f, 1.f}, shv = {0.f, 0.f, 0.f, 0.f};
    if (BN) {
        scv = *(const floatx4*)&ss[k0];
        shv = *(const floatx4*)&ss[HD + k0];
    }
    int kstep = k0 >> 5, g0 = (k0 >> 3) & 3, j0 = k0 & 7;
    int lbase = (kstep * 4 + g0) * 256 + j0;
#pragma unroll
    for (int i = 0; i < 4; i++) {
        int f = f0 + i * 1024;
        int m = f >> 7;
        floatx4 v = *(const floatx4*)&hin[n0 * HD + f];
        if (BN) {
            v = v * scv + shv;
            v.x = fmaxf(v.x, 0.f); v.y = fmaxf(v.y, 0.f);
            v.z = fmaxf(v.z, 0.f); v.w = fmaxf(v.w, 0.f);
        }
        unsigned long long pack = (unsigned long long)f2bf(v.x)
                                | ((unsigned long long)f2bf(v.y) << 16)
                                | ((unsigned long long)f2bf(v.z) << 32)
                                | ((unsigned long long)f2bf(v.w) << 48);
        *(unsigned long long*)&As[lbase + m * 8] = pack;
    }
    __syncthreads();
    int lane = t & 63, wv = t >> 6;
    int lanelo = lane & 15, g = lane >> 4;
    floatx4 acc[2][2] = {};
#pragma unroll
    for (int ks = 0; ks < 4; ks++) {
        short8 a0 = *(const short8*)&As[((ks * 4 + g) * 32 + lanelo) * 8];
        short8 a1 = *(const short8*)&As[((ks * 4 + g) * 32 + 16 + lanelo) * 8];
        short8 b0 = *(const short8*)&Wf[(((wv * 2 + 0) * 4 + ks) * 4 + g) * 128 + lanelo * 8];
        short8 b1 = *(const short8*)&Wf[(((wv * 2 + 1) * 4 + ks) * 4 + g) * 128 + lanelo * 8];
        acc[0][0] = __builtin_amdgcn_mfma_f32_16x16x32_bf16(a0, b0, acc[0][0], 0, 0, 0);
        acc[0][1] = __builtin_amdgcn_mfma_f32_16x16x32_bf16(a0, b1, acc[0][1], 0, 0, 0);
        acc[1][0] = __builtin_amdgcn_mfma_f32_16x16x32_bf16(a1, b0, acc[1][0], 0, 0, 0);
        acc[1][1] = __builtin_amdgcn_mfma_f32_16x16x32_bf16(a1, b1, acc[1][1], 0, 0, 0);
    }
#pragma unroll
    for (int ms = 0; ms < 2; ms++)
#pragma unroll
        for (int ns = 0; ns < 2; ns++) {
            int colc = wv * 32 + ns * 16 + lanelo;
#pragma unroll
            for (int r = 0; r < 4; r++) {
                int row = n0 + ms * 16 + g * 4 + r;
                hw[row * HD + colc] = acc[ms][ns][r];
            }
        }
}

// ---------------- CSR gather: A[n] = sum_in B[s]*dinv[s]*dinv[n] + B[n]*dinv[n]^2 + bias
__global__ __launch_bounds__(256) void k_gather(const int* __restrict__ rowptr,
                                                const int* __restrict__ col,
                                                const float* __restrict__ dinv,
                                                const float* __restrict__ B,
                                                const float* __restrict__ bias,
                                                float* __restrict__ A) {
    int t = threadIdx.x;
    int n = blockIdx.x * 8 + (t >> 5);   // 8 nodes/block
    int c4 = (t & 31) * 4;
    float dd = dinv[n];
    floatx4 acc = *(const floatx4*)&B[n * HD + c4];
    acc = acc * (dd * dd) + *(const floatx4*)&bias[c4];
    int j0 = rowptr[n], j1 = rowptr[n + 1];
    for (int j = j0; j < j1; j++) {
        int s = col[j];
        float nm = dinv[s] * dd;
        floatx4 v = *(const floatx4*)&B[s * HD + c4];
        acc += v * nm;
    }
    *(floatx4*)&A[n * HD + c4] = acc;
}

// ---------------- BN statistics (parallel, LDS-reduced) ----------------
__global__ __launch_bounds__(256) void k_bn_stats(const float* __restrict__ h,
                                                  float* __restrict__ sums) {
    __shared__ float ls[256];
    int t = threadIdx.x;
    ls[t] = 0.0f;
    __syncthreads();
    int c4 = (t & 31) * 4;
    floatx4 s = {0.f, 0.f, 0.f, 0.f}, sq = {0.f, 0.f, 0.f, 0.f};
    for (int n = blockIdx.x * 8 + (t >> 5); n < NN; n += gridDim.x * 8) {
        floatx4 v = *(const floatx4*)&h[n * HD + c4];
        s += v;
        sq += v * v;
    }
#pragma unroll
    for (int i = 0; i < 4; i++) {
        atomicAdd(&ls[c4 + i], s[i]);
        atomicAdd(&ls[HD + c4 + i], sq[i]);
    }
    __syncthreads();
    atomicAdd(&sums[t], ls[t]);
}

__global__ __launch_bounds__(128) void k_bn_fin(const float* __restrict__ sums,
                                                const float* __restrict__ gamma,
                                                const float* __restrict__ beta,
                                                float* __restrict__ ss) {
    int c = threadIdx.x;
    float inv_n = 1.0f / (float)NN;
    float mu = sums[c] * inv_n;
    float var = sums[HD + c] * inv_n - mu * mu;
    float sc = gamma[c] * rsqrtf(var + BN_EPS);
    ss[c] = sc;
    ss[HD + c] = beta[c] - mu * sc;
}

// ---------------- atomic-free pooling: one block per graph ----------------
__global__ __launch_bounds__(128) void k_pool_g(const float* __restrict__ h,
                                                const float* __restrict__ ss,
                                                const int* __restrict__ gstart,
                                                float* __restrict__ gfeat) {
    int g = blockIdx.x;
    int c = threadIdx.x;
    int n0 = gstart[g], n1 = gstart[g + 1];
    float sc = ss[c], sh = ss[HD + c];
    float s = 0.0f, mx = 0.0f;   // post-ReLU values >= 0; 0 matches empty-seg guard
    for (int n = n0; n < n1; n++) {
        float v = fmaxf(h[n * HD + c] * sc + sh, 0.0f);
        s += v;
        mx = fmaxf(mx, v);
    }
    float cntf = (float)(n1 - n0);
    gfeat[g * 256 + c] = s / fmaxf(cntf, 1.0f);
    gfeat[g * 256 + HD + c] = mx;
}

// ---------------- fused MLP head ----------------
__global__ __launch_bounds__(128) void k_mlp(const float* __restrict__ gfeat,
                                             const float* __restrict__ w1,
                                             const float* __restrict__ b1,
                                             const float* __restrict__ w2,
                                             const float* __restrict__ b2,
                                             const float* __restrict__ w3,
                                             const float* __restrict__ b3,
                                             float* __restrict__ out) {
    __shared__ float gs[2 * HD];
    __shared__ float h1[HD];
    __shared__ float h2[64];
    int t = threadIdx.x;
    int g = blockIdx.x;
    gs[t] = gfeat[g * (2 * HD) + t];
    gs[HD + t] = gfeat[g * (2 * HD) + HD + t];
    __syncthreads();
    float a1 = b1[t];
    for (int k = 0; k < 2 * HD; k++) a1 += gs[k] * w1[k * HD + t];
    h1[t] = fmaxf(a1, 0.0f);
    __syncthreads();
    if (t < 64) {
        float a2 = b2[t];
        for (int k = 0; k < HD; k++) a2 += h1[k] * w2[k * 64 + t];
        h2[t] = fmaxf(a2, 0.0f);
    }
    __syncthreads();
    if (t == 0) {
        float a3 = b3[0];
        for (int k = 0; k < 64; k++) a3 += h2[k] * w3[k];
        out[g] = a3;
    }
}

extern "C" void kernel_launch(void* const* d_in, const int* in_sizes, int n_in,
                              void* d_out, int out_size, void* d_ws, size_t ws_size,
                              hipStream_t stream) {
    const float* x      = (const float*)d_in[0];
    const int*   eidx   = (const int*)d_in[1];   // [2, NE]: src then dst
    const int*   batch  = (const int*)d_in[2];
    const float* emb_W  = (const float*)d_in[3];
    const float* emb_b  = (const float*)d_in[4];
    const float* conv_W = (const float*)d_in[5]; // [3,128,128]
    const float* conv_b = (const float*)d_in[6]; // [3,128]
    const float* gamma  = (const float*)d_in[7];
    const float* beta   = (const float*)d_in[8];
    const float* w1     = (const float*)d_in[9];
    const float* b1     = (const float*)d_in[10];
    const float* w2     = (const float*)d_in[11];
    const float* b2     = (const float*)d_in[12];
    const float* w3     = (const float*)d_in[13];
    const float* b3     = (const float*)d_in[14];
    float* out = (float*)d_out;

    const int* src = eidx;
    const int* dst = eidx + NE;

    // workspace carve-up
    float* ws    = (float*)d_ws;
    float* A     = ws;                  // [NN*HD]
    float* B     = A + NN * HD;         // [NN*HD]
    float* dinv  = B + NN * HD;         // [NN]
    float* bnsum = dinv + NN;           // [256]
    float* bnss  = bnsum + 256;         // [256]
    int*   gstart= (int*)(bnss + 256);  // [NG+1]
    int*   degi  = gstart + NG + 1;     // [NN]
    int*   cursor= degi + NN;           // [NN]  (contiguous with degi, 1 memset)
    int*   rowptr= cursor + NN;         // [NN+1]
    int*   part  = rowptr + NN + 1;     // [NSCAN]
    int*   col   = part + NSCAN;        // [NE]
    unsigned short* WfE = (unsigned short*)(col + NE);  // [12288]
    unsigned short* WfC = WfE + 12288;                  // [3*16384]

    // ---- CSR build + dinv + graph bounds ----
    hipMemsetAsync(degi, 0, 2 * NN * sizeof(int), stream);  // degi + cursor
    k_hist<<<(NE + 255) / 256, 256, 0, stream>>>(dst, degi);
    k_dinv<<<(NN + 255) / 256, 256, 0, stream>>>(degi, dinv);
    k_scan1<<<NSCAN, 256, 0, stream>>>(degi, part);
    k_scan2<<<1, 512, 0, stream>>>(part);
    k_scan3<<<NSCAN, 256, 0, stream>>>(degi, part, rowptr);
    k_fill<<<(NE + 255) / 256, 256, 0, stream>>>(src, dst, rowptr, cursor, col);
    k_bounds<<<(NN + 255) / 256, 256, 0, stream>>>(batch, gstart);

    // ---- weight pre-pack ----
    k_wemb<<<(12288 + 255) / 256, 256, 0, stream>>>(emb_W, WfE);
    k_wconv<<<(NL * 16384 + 255) / 256, 256, 0, stream>>>(conv_W, WfC);

    // ---- embedding ----
    k_emb<<<NN / 32, 256, 0, stream>>>(x, WfE, emb_b, A);

    for (int l = 0; l < NL; l++) {
        if (l == 0)
            k_conv<false><<<NN / 32, 256, 0, stream>>>(A, nullptr, WfC, B);
        else
            k_conv<true><<<NN / 32, 256, 0, stream>>>(A, bnss, WfC + l * 16384, B);
        k_gather<<<NN / 8, 256, 0, stream>>>(rowptr, col, dinv, B, conv_b + l * HD, A);
        hipMemsetAsync(bnsum, 0, 256 * sizeof(float), stream);
        k_bn_stats<<<512, 256, 0, stream>>>(A, bnsum);
        k_bn_fin<<<1, 128, 0, stream>>>(bnsum, gamma + l * HD, beta + l * HD, bnss);
    }

    // ---- pooling (BN of layer 2 fused, no atomics) ----
    float* gfeat = B;  // reuse
    k_pool_g<<<NG, 128, 0, stream>>>(A, bnss, gstart, gfeat);

    k_mlp<<<NG, 128, 0, stream>>>(gfeat, w1, b1, w2, b2, w3, b3, out);
}

// Round 6
// 440.502 us; speedup vs baseline: 3.8605x; 1.2511x over previous
//
#include <hip/hip_runtime.h>

#define NN 100000   // nodes
#define NE 600000   // edges
#define NG 4096     // graphs
#define FIN 74
#define HD 128
#define NL 3
#define BN_EPS 1e-5f
#define NSCAN 391   // ceil(NN/256)

typedef __attribute__((ext_vector_type(8))) short short8;
typedef __attribute__((ext_vector_type(4))) float floatx4;
typedef __attribute__((ext_vector_type(8))) unsigned short bf16x8;  // NOTE: ushort4/8 collide with HIP headers
typedef __attribute__((ext_vector_type(4))) unsigned short bf16x4;

__device__ __forceinline__ unsigned short f2bf(float f) {
    unsigned u = __float_as_uint(f);
    u += 0x7fff + ((u >> 16) & 1);   // round-to-nearest-even
    return (unsigned short)(u >> 16);
}
__device__ __forceinline__ float bf2f(unsigned short u) {
    return __uint_as_float(((unsigned)u) << 16);
}

// ---------------- CSR build ----------------
__global__ __launch_bounds__(256) void k_hist(const int* __restrict__ dst,
                                              int* __restrict__ degi) {
    int e = blockIdx.x * 256 + threadIdx.x;
    if (e < NE) atomicAdd(&degi[dst[e]], 1);
}

__global__ __launch_bounds__(256) void k_scan1(const int* __restrict__ degi,
                                               int* __restrict__ part) {
    __shared__ int s[256];
    int t = threadIdx.x;
    int idx = blockIdx.x * 256 + t;
    s[t] = (idx < NN) ? degi[idx] : 0;
    __syncthreads();
    for (int off = 128; off > 0; off >>= 1) {
        if (t < off) s[t] += s[t + off];
        __syncthreads();
    }
    if (t == 0) part[blockIdx.x] = s[0];
}

__global__ __launch_bounds__(512) void k_scan2(int* __restrict__ part) {
    __shared__ int s[512];
    int t = threadIdx.x;
    s[t] = (t < NSCAN) ? part[t] : 0;
    __syncthreads();
    for (int off = 1; off < 512; off <<= 1) {
        int v = s[t];
        int a = (t >= off) ? s[t - off] : 0;
        __syncthreads();
        s[t] = v + a;
        __syncthreads();
    }
    if (t < NSCAN) part[t] = (t > 0) ? s[t - 1] : 0;  // exclusive
}

// scan3 + dinv fused
__global__ __launch_bounds__(256) void k_scan3(const int* __restrict__ degi,
                                               const int* __restrict__ part,
                                               int* __restrict__ rowptr,
                                               float* __restrict__ dinv) {
    __shared__ int s[256];
    int t = threadIdx.x;
    int idx = blockIdx.x * 256 + t;
    int v = (idx < NN) ? degi[idx] : 0;
    s[t] = v;
    __syncthreads();
    for (int off = 1; off < 256; off <<= 1) {
        int x = s[t];
        int a = (t >= off) ? s[t - off] : 0;
        __syncthreads();
        s[t] = x + a;
        __syncthreads();
    }
    if (idx < NN) {
        rowptr[idx] = part[blockIdx.x] + (s[t] - v);
        dinv[idx] = rsqrtf((float)v + 1.0f);  // +1 self-loop
    }
    if (idx == 0) rowptr[NN] = NE;
}

__global__ __launch_bounds__(256) void k_fill(const int* __restrict__ src,
                                              const int* __restrict__ dst,
                                              const int* __restrict__ rowptr,
                                              int* __restrict__ cursor,
                                              int* __restrict__ col) {
    int e = blockIdx.x * 256 + threadIdx.x;
    if (e >= NE) return;
    int d = dst[e];
    int pos = rowptr[d] + atomicAdd(&cursor[d], 1);
    col[pos] = src[e];
}

// ---------------- graph boundaries from sorted batch ----------------
__global__ __launch_bounds__(256) void k_bounds(const int* __restrict__ batch,
                                                int* __restrict__ gstart) {
    int n = blockIdx.x * 256 + threadIdx.x;
    if (n >= NN) return;
    int b = batch[n];
    int bp = (n == 0) ? -1 : batch[n - 1];
    for (int g = bp + 1; g <= b; g++) gstart[g] = n;
    if (n == NN - 1)
        for (int g = b + 1; g <= NG; g++) gstart[g] = NN;
}

// ---------------- weight fragment pre-pack (bf16), emb + conv fused ----------------
__global__ __launch_bounds__(256) void k_wpack(const float* __restrict__ embW,
                                               const float* __restrict__ convW,
                                               unsigned short* __restrict__ WfE,
                                               unsigned short* __restrict__ WfC) {
    int d = blockIdx.x * 256 + threadIdx.x;
    if (d < 12288) {
        int inner = d & 511, outer = d >> 9;
        int kstep = outer % 3, nt = outer / 3;
        int g = inner >> 7, n = (inner >> 3) & 15, j = inner & 7;
        int k = kstep * 32 + g * 8 + j;
        float v = (k < FIN) ? embW[k * HD + nt * 16 + n] : 0.0f;
        WfE[d] = f2bf(v);
    } else {
        int e = d - 12288;
        if (e >= NL * 16384) return;
        int layer = e >> 14, r = e & 16383;
        int j = r & 7, n = (r >> 3) & 15, g = (r >> 7) & 3, kstep = (r >> 9) & 3, nt = r >> 11;
        int k = kstep * 32 + g * 8 + j;
        WfC[e] = f2bf(convW[layer * 16384 + k * HD + nt * 16 + n]);
    }
}

// ---------------- embedding MFMA: A = relu(x @ W + b), bf16 out ----------------
// LDS: staging frag layout combo c=kstep*4+g (0..11), stride 264 hw; epilogue 32x132
__global__ __launch_bounds__(256) void k_emb(const float* __restrict__ x,
                                             const unsigned short* __restrict__ Wf,
                                             const float* __restrict__ b,
                                             unsigned short* __restrict__ hA) {
    __shared__ __align__(16) unsigned short As[4224];
    int t = threadIdx.x;
    int n0 = blockIdx.x * 32;
    for (int f = t; f < 3072; f += 256) {
        int m = f / 96, kp = f % 96;
        float v = (kp < FIN) ? x[(n0 + m) * FIN + kp] : 0.0f;
        int kstep = kp >> 5, g = (kp >> 3) & 3, j = kp & 7;
        As[(kstep * 4 + g) * 264 + m * 8 + j] = f2bf(v);
    }
    __syncthreads();
    int lane = t & 63, wv = t >> 6;
    int lanelo = lane & 15, g = lane >> 4;
    floatx4 acc[2][2] = {};
#pragma unroll
    for (int kstep = 0; kstep < 3; kstep++) {
        short8 a0 = *(const short8*)&As[(kstep * 4 + g) * 264 + lanelo * 8];
        short8 a1 = *(const short8*)&As[(kstep * 4 + g) * 264 + 128 + lanelo * 8];
        short8 b0 = *(const short8*)&Wf[(((wv * 2 + 0) * 3 + kstep) * 4 + g) * 128 + lanelo * 8];
        short8 b1 = *(const short8*)&Wf[(((wv * 2 + 1) * 3 + kstep) * 4 + g) * 128 + lanelo * 8];
        acc[0][0] = __builtin_amdgcn_mfma_f32_16x16x32_bf16(a0, b0, acc[0][0], 0, 0, 0);
        acc[0][1] = __builtin_amdgcn_mfma_f32_16x16x32_bf16(a0, b1, acc[0][1], 0, 0, 0);
        acc[1][0] = __builtin_amdgcn_mfma_f32_16x16x32_bf16(a1, b0, acc[1][0], 0, 0, 0);
        acc[1][1] = __builtin_amdgcn_mfma_f32_16x16x32_bf16(a1, b1, acc[1][1], 0, 0, 0);
    }
    __syncthreads();  // frag reads done; reuse As as output tile (stride 132)
#pragma unroll
    for (int ns = 0; ns < 2; ns++) {
        int colc = wv * 32 + ns * 16 + lanelo;
        float bias = b[colc];
#pragma unroll
        for (int ms = 0; ms < 2; ms++)
#pragma unroll
            for (int r = 0; r < 4; r++) {
                int rowl = ms * 16 + g * 4 + r;
                As[rowl * 132 + colc] = f2bf(fmaxf(acc[ms][ns][r] + bias, 0.0f));
            }
    }
    __syncthreads();
#pragma unroll
    for (int i = 0; i < 2; i++) {
        int f = t * 8 + i * 2048;
        int m = f >> 7, c = f & 127;
        bf16x4 lo = *(const bf16x4*)&As[m * 132 + c];
        bf16x4 hi = *(const bf16x4*)&As[m * 132 + c + 4];
        bf16x8 o = {lo.x, lo.y, lo.z, lo.w, hi.x, hi.y, hi.z, hi.w};
        *(bf16x8*)&hA[n0 * HD + f] = o;
    }
}

// ---------------- conv MFMA: B' = (act(A) @ W) * dinv[row], bf16 in/out ----------------
template <bool BN>
__global__ __launch_bounds__(256) void k_conv(const unsigned short* __restrict__ hin,
                                              const float* __restrict__ ss,
                                              const unsigned short* __restrict__ Wf,
                                              const float* __restrict__ dinv,
                                              unsigned short* __restrict__ hw) {
    __shared__ __align__(16) unsigned short As[4224];
    __shared__ float dinvs[32];
    int t = threadIdx.x;
    int n0 = blockIdx.x * 32;
    if (t < 32) dinvs[t] = dinv[n0 + t];
    int f0 = t * 8;
    int k0 = f0 & 127;                  // same for both staging iterations
    float sc[8], sh[8];
    if (BN) {
        floatx4 s0 = *(const floatx4*)&ss[k0];
        floatx4 s1 = *(const floatx4*)&ss[k0 + 4];
        floatx4 h0 = *(const floatx4*)&ss[HD + k0];
        floatx4 h1 = *(const floatx4*)&ss[HD + k0 + 4];
        sc[0] = s0.x; sc[1] = s0.y; sc[2] = s0.z; sc[3] = s0.w;
        sc[4] = s1.x; sc[5] = s1.y; sc[6] = s1.z; sc[7] = s1.w;
        sh[0] = h0.x; sh[1] = h0.y; sh[2] = h0.z; sh[3] = h0.w;
        sh[4] = h1.x; sh[5] = h1.y; sh[6] = h1.z; sh[7] = h1.w;
    }
    int combo = (k0 >> 5) * 4 + ((k0 >> 3) & 3);
#pragma unroll
    for (int i = 0; i < 2; i++) {
        int f = f0 + i * 2048;
        int m = f >> 7;
        bf16x8 u = *(const bf16x8*)&hin[n0 * HD + f];
        bf16x8 o;
        if (BN) {
#pragma unroll
            for (int jj = 0; jj < 8; jj++) {
                float v = fmaxf(bf2f(u[jj]) * sc[jj] + sh[jj], 0.0f);
                o[jj] = f2bf(v);
            }
        } else {
            o = u;
        }
        *(bf16x8*)&As[combo * 264 + m * 8] = o;
    }
    __syncthreads();
    int lane = t & 63, wv = t >> 6;
    int lanelo = lane & 15, g = lane >> 4;
    floatx4 acc[2][2] = {};
#pragma unroll
    for (int ks = 0; ks < 4; ks++) {
        short8 a0 = *(const short8*)&As[(ks * 4 + g) * 264 + lanelo * 8];
        short8 a1 = *(const short8*)&As[(ks * 4 + g) * 264 + 128 + lanelo * 8];
        short8 b0 = *(const short8*)&Wf[(((wv * 2 + 0) * 4 + ks) * 4 + g) * 128 + lanelo * 8];
        short8 b1 = *(const short8*)&Wf[(((wv * 2 + 1) * 4 + ks) * 4 + g) * 128 + lanelo * 8];
        acc[0][0] = __builtin_amdgcn_mfma_f32_16x16x32_bf16(a0, b0, acc[0][0], 0, 0, 0);
        acc[0][1] = __builtin_amdgcn_mfma_f32_16x16x32_bf16(a0, b1, acc[0][1], 0, 0, 0);
        acc[1][0] = __builtin_amdgcn_mfma_f32_16x16x32_bf16(a1, b0, acc[1][0], 0, 0, 0);
        acc[1][1] = __builtin_amdgcn_mfma_f32_16x16x32_bf16(a1, b1, acc[1][1], 0, 0, 0);
    }
    __syncthreads();  // reuse As as output tile
#pragma unroll
    for (int ms = 0; ms < 2; ms++)
#pragma unroll
        for (int ns = 0; ns < 2; ns++) {
            int colc = wv * 32 + ns * 16 + lanelo;
#pragma unroll
            for (int r = 0; r < 4; r++) {
                int rowl = ms * 16 + g * 4 + r;
                As[rowl * 132 + colc] = f2bf(acc[ms][ns][r] * dinvs[rowl]);
            }
        }
    __syncthreads();
#pragma unroll
    for (int i = 0; i < 2; i++) {
        int f = f0 + i * 2048;
        int m = f >> 7, c = f & 127;
        bf16x4 lo = *(const bf16x4*)&As[m * 132 + c];
        bf16x4 hi = *(const bf16x4*)&As[m * 132 + c + 4];
        bf16x8 o = {lo.x, lo.y, lo.z, lo.w, hi.x, hi.y, hi.z, hi.w};
        *(bf16x8*)&hw[n0 * HD + f] = o;
    }
}

// ---------------- CSR gather (bf16): A[n] = (B'[n] + sum_in B'[s]) * dinv[n] + bias
__global__ __launch_bounds__(256) void k_gather(const int* __restrict__ rowptr,
                                                const int* __restrict__ col,
                                                const float* __restrict__ dinv,
                                                const unsigned short* __restrict__ B,
                                                const float* __restrict__ bias,
                                                unsigned short* __restrict__ A) {
    int t = threadIdx.x;
    int n = blockIdx.x * 16 + (t >> 4);  // 16 nodes/block, 16 lanes/node
    int c8 = (t & 15) * 8;
    bf16x8 u = *(const bf16x8*)&B[n * HD + c8];
    float acc[8];
#pragma unroll
    for (int i = 0; i < 8; i++) acc[i] = bf2f(u[i]);
    int j0 = rowptr[n], j1 = rowptr[n + 1];
    int j = j0;
    for (; j + 1 < j1; j += 2) {   // 2 edges in flight
        int s0 = col[j], s1 = col[j + 1];
        bf16x8 v0 = *(const bf16x8*)&B[s0 * HD + c8];
        bf16x8 v1 = *(const bf16x8*)&B[s1 * HD + c8];
#pragma unroll
        for (int i = 0; i < 8; i++) acc[i] += bf2f(v0[i]) + bf2f(v1[i]);
    }
    if (j < j1) {
        int s = col[j];
        bf16x8 v = *(const bf16x8*)&B[s * HD + c8];
#pragma unroll
        for (int i = 0; i < 8; i++) acc[i] += bf2f(v[i]);
    }
    float dd = dinv[n];
    floatx4 b0 = *(const floatx4*)&bias[c8];
    floatx4 b1 = *(const floatx4*)&bias[c8 + 4];
    bf16x8 o;
    o[0] = f2bf(acc[0] * dd + b0.x); o[1] = f2bf(acc[1] * dd + b0.y);
    o[2] = f2bf(acc[2] * dd + b0.z); o[3] = f2bf(acc[3] * dd + b0.w);
    o[4] = f2bf(acc[4] * dd + b1.x); o[5] = f2bf(acc[5] * dd + b1.y);
    o[6] = f2bf(acc[6] * dd + b1.z); o[7] = f2bf(acc[7] * dd + b1.w);
    *(bf16x8*)&A[n * HD + c8] = o;
}

// ---------------- BN statistics (bf16 input) ----------------
__global__ __launch_bounds__(256) void k_bn_stats(const unsigned short* __restrict__ h,
                                                  float* __restrict__ sums) {
    __shared__ float ls[256];
    int t = threadIdx.x;
    ls[t] = 0.0f;
    __syncthreads();
    int c8 = (t & 15) * 8;
    float s[8] = {}, sq[8] = {};
    for (int n = blockIdx.x * 16 + (t >> 4); n < NN; n += gridDim.x * 16) {
        bf16x8 u = *(const bf16x8*)&h[n * HD + c8];
#pragma unroll
        for (int i = 0; i < 8; i++) {
            float v = bf2f(u[i]);
            s[i] += v;
            sq[i] += v * v;
        }
    }
#pragma unroll
    for (int i = 0; i < 8; i++) {
        atomicAdd(&ls[c8 + i], s[i]);
        atomicAdd(&ls[HD + c8 + i], sq[i]);
    }
    __syncthreads();
    atomicAdd(&sums[t], ls[t]);
}

__global__ __launch_bounds__(128) void k_bn_fin(const float* __restrict__ sums,
                                                const float* __restrict__ gamma,
                                                const float* __restrict__ beta,
                                                float* __restrict__ ss) {
    int c = threadIdx.x;
    float inv_n = 1.0f / (float)NN;
    float mu = sums[c] * inv_n;
    float var = sums[HD + c] * inv_n - mu * mu;
    float sc = gamma[c] * rsqrtf(var + BN_EPS);
    ss[c] = sc;
    ss[HD + c] = beta[c] - mu * sc;
}

// ---------------- atomic-free pooling: one block per graph (bf16 input) ----------------
__global__ __launch_bounds__(128) void k_pool_g(const unsigned short* __restrict__ h,
                                                const float* __restrict__ ss,
                                                const int* __restrict__ gstart,
                                                float* __restrict__ gfeat) {
    int g = blockIdx.x;
    int c = threadIdx.x;
    int n0 = gstart[g], n1 = gstart[g + 1];
    float sc = ss[c], sh = ss[HD + c];
    float s = 0.0f, mx = 0.0f;   // post-ReLU >= 0; 0 matches empty-seg guard
    for (int n = n0; n < n1; n++) {
        float v = fmaxf(bf2f(h[n * HD + c]) * sc + sh, 0.0f);
        s += v;
        mx = fmaxf(mx, v);
    }
    float cntf = (float)(n1 - n0);
    gfeat[g * 256 + c] = s / fmaxf(cntf, 1.0f);
    gfeat[g * 256 + HD + c] = mx;
}

// ---------------- fused MLP head: 8 graphs/block (8x weight reuse) ----------------
__global__ __launch_bounds__(128) void k_mlp(const float* __restrict__ gfeat,
                                             const float* __restrict__ w1,
                                             const float* __restrict__ b1,
                                             const float* __restrict__ w2,
                                             const float* __restrict__ b2,
                                             const float* __restrict__ w3,
                                             const float* __restrict__ b3,
                                             float* __restrict__ out) {
    __shared__ float gs[2048];   // 8 x 256
    __shared__ float hs[1024];   // 8 x 128
    __shared__ float h2s[512];   // 8 x 64
    int t = threadIdx.x;
    int g0 = blockIdx.x * 8;
    for (int f = t; f < 2048; f += 128) gs[f] = gfeat[g0 * 256 + f];
    __syncthreads();
    float a1[8];
#pragma unroll
    for (int gi = 0; gi < 8; gi++) a1[gi] = b1[t];
#pragma unroll 4
    for (int k = 0; k < 256; k++) {
        float w = w1[k * HD + t];
#pragma unroll
        for (int gi = 0; gi < 8; gi++) a1[gi] += gs[gi * 256 + k] * w;
    }
#pragma unroll
    for (int gi = 0; gi < 8; gi++) hs[gi * 128 + t] = fmaxf(a1[gi], 0.0f);
    __syncthreads();
    if (t < 64) {
        float a2[8];
#pragma unroll
        for (int gi = 0; gi < 8; gi++) a2[gi] = b2[t];
#pragma unroll 4
        for (int k = 0; k < 128; k++) {
            float w = w2[k * 64 + t];
#pragma unroll
            for (int gi = 0; gi < 8; gi++) a2[gi] += hs[gi * 128 + k] * w;
        }
#pragma unroll
        for (int gi = 0; gi < 8; gi++) h2s[gi * 64 + t] = fmaxf(a2[gi], 0.0f);
    }
    __syncthreads();
    if (t < 8) {
        float a3 = b3[0];
        for (int k = 0; k < 64; k++) a3 += h2s[t * 64 + k] * w3[k];
        out[g0 + t] = a3;
    }
}

extern "C" void kernel_launch(void* const* d_in, const int* in_sizes, int n_in,
                              void* d_out, int out_size, void* d_ws, size_t ws_size,
                              hipStream_t stream) {
    const float* x      = (const float*)d_in[0];
    const int*   eidx   = (const int*)d_in[1];   // [2, NE]: src then dst
    const int*   batch  = (const int*)d_in[2];
    const float* emb_W  = (const float*)d_in[3];
    const float* emb_b  = (const float*)d_in[4];
    const float* conv_W = (const float*)d_in[5];
    const float* conv_b = (const float*)d_in[6];
    const float* gamma  = (const float*)d_in[7];
    const float* beta   = (const float*)d_in[8];
    const float* w1     = (const float*)d_in[9];
    const float* b1     = (const float*)d_in[10];
    const float* w2     = (const float*)d_in[11];
    const float* b2     = (const float*)d_in[12];
    const float* w3     = (const float*)d_in[13];
    const float* b3     = (const float*)d_in[14];
    float* out = (float*)d_out;

    const int* src = eidx;
    const int* dst = eidx + NE;

    // workspace carve-up
    unsigned short* A = (unsigned short*)d_ws;       // [NN*HD] bf16
    unsigned short* B = A + NN * HD;                 // [NN*HD] bf16
    float* dinv  = (float*)(B + NN * HD);            // [NN]
    float* bnsum = dinv + NN;                        // [256]
    float* bnss  = bnsum + 256;                      // [256]
    float* gfeat = bnss + 256;                       // [NG*256]
    int*   gstart= (int*)(gfeat + NG * 256);         // [NG+1]
    int*   degi  = gstart + NG + 1;                  // [NN]
    int*   cursor= degi + NN;                        // [NN] (contiguous, 1 memset)
    int*   rowptr= cursor + NN;                      // [NN+1]
    int*   part  = rowptr + NN + 1;                  // [NSCAN]
    int*   col   = part + NSCAN;                     // [NE]
    unsigned short* WfE = (unsigned short*)(col + NE);  // [12288]
    unsigned short* WfC = WfE + 12288;                  // [3*16384]

    // ---- CSR build + dinv + graph bounds + weight pack ----
    (void)hipMemsetAsync(degi, 0, 2 * NN * sizeof(int), stream);  // degi + cursor
    k_hist<<<(NE + 255) / 256, 256, 0, stream>>>(dst, degi);
    k_scan1<<<NSCAN, 256, 0, stream>>>(degi, part);
    k_scan2<<<1, 512, 0, stream>>>(part);
    k_scan3<<<NSCAN, 256, 0, stream>>>(degi, part, rowptr, dinv);
    k_fill<<<(NE + 255) / 256, 256, 0, stream>>>(src, dst, rowptr, cursor, col);
    k_bounds<<<(NN + 255) / 256, 256, 0, stream>>>(batch, gstart);
    k_wpack<<<240, 256, 0, stream>>>(emb_W, conv_W, WfE, WfC);

    // ---- embedding (bf16 out) ----
    k_emb<<<NN / 32, 256, 0, stream>>>(x, WfE, emb_b, A);

    for (int l = 0; l < NL; l++) {
        if (l == 0)
            k_conv<false><<<NN / 32, 256, 0, stream>>>(A, nullptr, WfC, dinv, B);
        else
            k_conv<true><<<NN / 32, 256, 0, stream>>>(A, bnss, WfC + l * 16384, dinv, B);
        k_gather<<<NN / 16, 256, 0, stream>>>(rowptr, col, dinv, B, conv_b + l * HD, A);
        (void)hipMemsetAsync(bnsum, 0, 256 * sizeof(float), stream);
        k_bn_stats<<<512, 256, 0, stream>>>(A, bnsum);
        k_bn_fin<<<1, 128, 0, stream>>>(bnsum, gamma + l * HD, beta + l * HD, bnss);
    }

    // ---- pooling (BN of last layer fused, no atomics) ----
    k_pool_g<<<NG, 128, 0, stream>>>(A, bnss, gstart, gfeat);

    k_mlp<<<NG / 8, 128, 0, stream>>>(gfeat, w1, b1, w2, b2, w3, b3, out);
}

// Round 8
// 429.119 us; speedup vs baseline: 3.9629x; 1.0265x over previous
//
#include <hip/hip_runtime.h>

#define NN 100000   // nodes
#define NE 600000   // edges
#define NG 4096     // graphs
#define FIN 74
#define HD 128
#define NL 3
#define BN_EPS 1e-5f
#define NSCAN 391   // ceil(NN/256)

typedef __attribute__((ext_vector_type(8))) short short8;
typedef __attribute__((ext_vector_type(4))) float floatx4;
typedef __attribute__((ext_vector_type(8))) unsigned short bf16x8;  // ushort4/8 collide with HIP headers
typedef __attribute__((ext_vector_type(4))) unsigned short bf16x4;

__device__ __forceinline__ unsigned short f2bf(float f) {
    unsigned u = __float_as_uint(f);
    u += 0x7fff + ((u >> 16) & 1);   // round-to-nearest-even
    return (unsigned short)(u >> 16);
}
__device__ __forceinline__ float bf2f(unsigned short u) {
    return __uint_as_float(((unsigned)u) << 16);
}

// ---------------- CSR build ----------------
__global__ __launch_bounds__(256) void k_hist(const int* __restrict__ dst,
                                              int* __restrict__ degi) {
    int e = blockIdx.x * 256 + threadIdx.x;
    if (e < NE) atomicAdd(&degi[dst[e]], 1);
}

__global__ __launch_bounds__(256) void k_scan1(const int* __restrict__ degi,
                                               int* __restrict__ part) {
    __shared__ int s[256];
    int t = threadIdx.x;
    int idx = blockIdx.x * 256 + t;
    s[t] = (idx < NN) ? degi[idx] : 0;
    __syncthreads();
    for (int off = 128; off > 0; off >>= 1) {
        if (t < off) s[t] += s[t + off];
        __syncthreads();
    }
    if (t == 0) part[blockIdx.x] = s[0];
}

__global__ __launch_bounds__(512) void k_scan2(int* __restrict__ part) {
    __shared__ int s[512];
    int t = threadIdx.x;
    s[t] = (t < NSCAN) ? part[t] : 0;
    __syncthreads();
    for (int off = 1; off < 512; off <<= 1) {
        int v = s[t];
        int a = (t >= off) ? s[t - off] : 0;
        __syncthreads();
        s[t] = v + a;
        __syncthreads();
    }
    if (t < NSCAN) part[t] = (t > 0) ? s[t - 1] : 0;  // exclusive
}

// scan3 + dinv fused
__global__ __launch_bounds__(256) void k_scan3(const int* __restrict__ degi,
                                               const int* __restrict__ part,
                                               int* __restrict__ rowptr,
                                               float* __restrict__ dinv) {
    __shared__ int s[256];
    int t = threadIdx.x;
    int idx = blockIdx.x * 256 + t;
    int v = (idx < NN) ? degi[idx] : 0;
    s[t] = v;
    __syncthreads();
    for (int off = 1; off < 256; off <<= 1) {
        int x = s[t];
        int a = (t >= off) ? s[t - off] : 0;
        __syncthreads();
        s[t] = x + a;
        __syncthreads();
    }
    if (idx < NN) {
        rowptr[idx] = part[blockIdx.x] + (s[t] - v);
        dinv[idx] = rsqrtf((float)v + 1.0f);  // +1 self-loop
    }
    if (idx == 0) rowptr[NN] = NE;
}

__global__ __launch_bounds__(256) void k_fill(const int* __restrict__ src,
                                              const int* __restrict__ dst,
                                              const int* __restrict__ rowptr,
                                              int* __restrict__ cursor,
                                              int* __restrict__ col) {
    int e = blockIdx.x * 256 + threadIdx.x;
    if (e >= NE) return;
    int d = dst[e];
    int pos = rowptr[d] + atomicAdd(&cursor[d], 1);
    col[pos] = src[e];
}

// ---------------- graph boundaries from sorted batch ----------------
__global__ __launch_bounds__(256) void k_bounds(const int* __restrict__ batch,
                                                int* __restrict__ gstart) {
    int n = blockIdx.x * 256 + threadIdx.x;
    if (n >= NN) return;
    int b = batch[n];
    int bp = (n == 0) ? -1 : batch[n - 1];
    for (int g = bp + 1; g <= b; g++) gstart[g] = n;
    if (n == NN - 1)
        for (int g = b + 1; g <= NG; g++) gstart[g] = NN;
}

// ---------------- weight fragment pre-pack (bf16), emb + conv fused ----------------
__global__ __launch_bounds__(256) void k_wpack(const float* __restrict__ embW,
                                               const float* __restrict__ convW,
                                               unsigned short* __restrict__ WfE,
                                               unsigned short* __restrict__ WfC) {
    int d = blockIdx.x * 256 + threadIdx.x;
    if (d < 12288) {
        int inner = d & 511, outer = d >> 9;
        int kstep = outer % 3, nt = outer / 3;
        int g = inner >> 7, n = (inner >> 3) & 15, j = inner & 7;
        int k = kstep * 32 + g * 8 + j;
        float v = (k < FIN) ? embW[k * HD + nt * 16 + n] : 0.0f;
        WfE[d] = f2bf(v);
    } else {
        int e = d - 12288;
        if (e >= NL * 16384) return;
        int layer = e >> 14, r = e & 16383;
        int j = r & 7, n = (r >> 3) & 15, g = (r >> 7) & 3, kstep = (r >> 9) & 3, nt = r >> 11;
        int k = kstep * 32 + g * 8 + j;
        WfC[e] = f2bf(convW[layer * 16384 + k * HD + nt * 16 + n]);
    }
}

// ---------------- embedding MFMA: A = relu(x @ W + b), bf16 out ----------------
__global__ __launch_bounds__(256) void k_emb(const float* __restrict__ x,
                                             const unsigned short* __restrict__ Wf,
                                             const float* __restrict__ b,
                                             unsigned short* __restrict__ hA) {
    __shared__ __align__(16) unsigned short As[4224];
    int t = threadIdx.x;
    int n0 = blockIdx.x * 32;
    for (int f = t; f < 3072; f += 256) {
        int m = f / 96, kp = f % 96;
        float v = (kp < FIN) ? x[(n0 + m) * FIN + kp] : 0.0f;
        int kstep = kp >> 5, g = (kp >> 3) & 3, j = kp & 7;
        As[(kstep * 4 + g) * 264 + m * 8 + j] = f2bf(v);
    }
    __syncthreads();
    int lane = t & 63, wv = t >> 6;
    int lanelo = lane & 15, g = lane >> 4;
    floatx4 acc[2][2] = {};
#pragma unroll
    for (int kstep = 0; kstep < 3; kstep++) {
        short8 a0 = *(const short8*)&As[(kstep * 4 + g) * 264 + lanelo * 8];
        short8 a1 = *(const short8*)&As[(kstep * 4 + g) * 264 + 128 + lanelo * 8];
        short8 b0 = *(const short8*)&Wf[(((wv * 2 + 0) * 3 + kstep) * 4 + g) * 128 + lanelo * 8];
        short8 b1 = *(const short8*)&Wf[(((wv * 2 + 1) * 3 + kstep) * 4 + g) * 128 + lanelo * 8];
        acc[0][0] = __builtin_amdgcn_mfma_f32_16x16x32_bf16(a0, b0, acc[0][0], 0, 0, 0);
        acc[0][1] = __builtin_amdgcn_mfma_f32_16x16x32_bf16(a0, b1, acc[0][1], 0, 0, 0);
        acc[1][0] = __builtin_amdgcn_mfma_f32_16x16x32_bf16(a1, b0, acc[1][0], 0, 0, 0);
        acc[1][1] = __builtin_amdgcn_mfma_f32_16x16x32_bf16(a1, b1, acc[1][1], 0, 0, 0);
    }
    __syncthreads();  // reuse As as output tile (stride 132)
#pragma unroll
    for (int ns = 0; ns < 2; ns++) {
        int colc = wv * 32 + ns * 16 + lanelo;
        float bias = b[colc];
#pragma unroll
        for (int ms = 0; ms < 2; ms++)
#pragma unroll
            for (int r = 0; r < 4; r++) {
                int rowl = ms * 16 + g * 4 + r;
                As[rowl * 132 + colc] = f2bf(fmaxf(acc[ms][ns][r] + bias, 0.0f));
            }
    }
    __syncthreads();
#pragma unroll
    for (int i = 0; i < 2; i++) {
        int f = t * 8 + i * 2048;
        int m = f >> 7, c = f & 127;
        bf16x4 lo = *(const bf16x4*)&As[m * 132 + c];
        bf16x4 hi = *(const bf16x4*)&As[m * 132 + c + 4];
        bf16x8 o = {lo.x, lo.y, lo.z, lo.w, hi.x, hi.y, hi.z, hi.w};
        *(bf16x8*)&hA[n0 * HD + f] = o;
    }
}

// ---------------- conv MFMA: B' = (act(A) @ W) * dinv[row], bf16 in/out ----------------
template <bool BN>
__global__ __launch_bounds__(256) void k_conv(const unsigned short* __restrict__ hin,
                                              const float* __restrict__ ss,
                                              const unsigned short* __restrict__ Wf,
                                              const float* __restrict__ dinv,
                                              unsigned short* __restrict__ hw) {
    __shared__ __align__(16) unsigned short As[4224];
    __shared__ float dinvs[32];
    int t = threadIdx.x;
    int n0 = blockIdx.x * 32;
    if (t < 32) dinvs[t] = dinv[n0 + t];
    int f0 = t * 8;
    int k0 = f0 & 127;
    float sc[8], sh[8];
    if (BN) {
        floatx4 s0 = *(const floatx4*)&ss[k0];
        floatx4 s1 = *(const floatx4*)&ss[k0 + 4];
        floatx4 h0 = *(const floatx4*)&ss[HD + k0];
        floatx4 h1 = *(const floatx4*)&ss[HD + k0 + 4];
        sc[0] = s0.x; sc[1] = s0.y; sc[2] = s0.z; sc[3] = s0.w;
        sc[4] = s1.x; sc[5] = s1.y; sc[6] = s1.z; sc[7] = s1.w;
        sh[0] = h0.x; sh[1] = h0.y; sh[2] = h0.z; sh[3] = h0.w;
        sh[4] = h1.x; sh[5] = h1.y; sh[6] = h1.z; sh[7] = h1.w;
    }
    int combo = (k0 >> 5) * 4 + ((k0 >> 3) & 3);
#pragma unroll
    for (int i = 0; i < 2; i++) {
        int f = f0 + i * 2048;
        int m = f >> 7;
        bf16x8 u = *(const bf16x8*)&hin[n0 * HD + f];
        bf16x8 o;
        if (BN) {
#pragma unroll
            for (int jj = 0; jj < 8; jj++) {
                float v = fmaxf(bf2f(u[jj]) * sc[jj] + sh[jj], 0.0f);
                o[jj] = f2bf(v);
            }
        } else {
            o = u;
        }
        *(bf16x8*)&As[combo * 264 + m * 8] = o;
    }
    __syncthreads();
    int lane = t & 63, wv = t >> 6;
    int lanelo = lane & 15, g = lane >> 4;
    floatx4 acc[2][2] = {};
#pragma unroll
    for (int ks = 0; ks < 4; ks++) {
        short8 a0 = *(const short8*)&As[(ks * 4 + g) * 264 + lanelo * 8];
        short8 a1 = *(const short8*)&As[(ks * 4 + g) * 264 + 128 + lanelo * 8];
        short8 b0 = *(const short8*)&Wf[(((wv * 2 + 0) * 4 + ks) * 4 + g) * 128 + lanelo * 8];
        short8 b1 = *(const short8*)&Wf[(((wv * 2 + 1) * 4 + ks) * 4 + g) * 128 + lanelo * 8];
        acc[0][0] = __builtin_amdgcn_mfma_f32_16x16x32_bf16(a0, b0, acc[0][0], 0, 0, 0);
        acc[0][1] = __builtin_amdgcn_mfma_f32_16x16x32_bf16(a0, b1, acc[0][1], 0, 0, 0);
        acc[1][0] = __builtin_amdgcn_mfma_f32_16x16x32_bf16(a1, b0, acc[1][0], 0, 0, 0);
        acc[1][1] = __builtin_amdgcn_mfma_f32_16x16x32_bf16(a1, b1, acc[1][1], 0, 0, 0);
    }
    __syncthreads();  // reuse As as output tile
#pragma unroll
    for (int ms = 0; ms < 2; ms++)
#pragma unroll
        for (int ns = 0; ns < 2; ns++) {
            int colc = wv * 32 + ns * 16 + lanelo;
#pragma unroll
            for (int r = 0; r < 4; r++) {
                int rowl = ms * 16 + g * 4 + r;
                As[rowl * 132 + colc] = f2bf(acc[ms][ns][r] * dinvs[rowl]);
            }
        }
    __syncthreads();
#pragma unroll
    for (int i = 0; i < 2; i++) {
        int f = f0 + i * 2048;
        int m = f >> 7, c = f & 127;
        bf16x4 lo = *(const bf16x4*)&As[m * 132 + c];
        bf16x4 hi = *(const bf16x4*)&As[m * 132 + c + 4];
        bf16x8 o = {lo.x, lo.y, lo.z, lo.w, hi.x, hi.y, hi.z, hi.w};
        *(bf16x8*)&hw[n0 * HD + f] = o;
    }
}

// ---------------- CSR gather (bf16): A[n] = (B'[n] + sum_in B'[s]) * dinv[n] + bias
__global__ __launch_bounds__(256) void k_gather(const int* __restrict__ rowptr,
                                                const int* __restrict__ col,
                                                const float* __restrict__ dinv,
                                                const unsigned short* __restrict__ B,
                                                const float* __restrict__ bias,
                                                unsigned short* __restrict__ A) {
    int t = threadIdx.x;
    int n = blockIdx.x * 16 + (t >> 4);  // 16 nodes/block, 16 lanes/node
    int c8 = (t & 15) * 8;
    bf16x8 u = *(const bf16x8*)&B[n * HD + c8];
    float acc[8];
#pragma unroll
    for (int i = 0; i < 8; i++) acc[i] = bf2f(u[i]);
    int j0 = rowptr[n], j1 = rowptr[n + 1];
    int j = j0;
    for (; j + 1 < j1; j += 2) {
        int s0 = col[j], s1 = col[j + 1];
        bf16x8 v0 = *(const bf16x8*)&B[s0 * HD + c8];
        bf16x8 v1 = *(const bf16x8*)&B[s1 * HD + c8];
#pragma unroll
        for (int i = 0; i < 8; i++) acc[i] += bf2f(v0[i]) + bf2f(v1[i]);
    }
    if (j < j1) {
        int s = col[j];
        bf16x8 v = *(const bf16x8*)&B[s * HD + c8];
#pragma unroll
        for (int i = 0; i < 8; i++) acc[i] += bf2f(v[i]);
    }
    float dd = dinv[n];
    floatx4 b0 = *(const floatx4*)&bias[c8];
    floatx4 b1 = *(const floatx4*)&bias[c8 + 4];
    bf16x8 o;
    o[0] = f2bf(acc[0] * dd + b0.x); o[1] = f2bf(acc[1] * dd + b0.y);
    o[2] = f2bf(acc[2] * dd + b0.z); o[3] = f2bf(acc[3] * dd + b0.w);
    o[4] = f2bf(acc[4] * dd + b1.x); o[5] = f2bf(acc[5] * dd + b1.y);
    o[6] = f2bf(acc[6] * dd + b1.z); o[7] = f2bf(acc[7] * dd + b1.w);
    *(bf16x8*)&A[n * HD + c8] = o;
}

// ---------------- BN statistics (bf16 input) ----------------
__global__ __launch_bounds__(256) void k_bn_stats(const unsigned short* __restrict__ h,
                                                  float* __restrict__ sums) {
    __shared__ float ls[256];
    int t = threadIdx.x;
    ls[t] = 0.0f;
    __syncthreads();
    int c8 = (t & 15) * 8;
    float s[8] = {}, sq[8] = {};
    for (int n = blockIdx.x * 16 + (t >> 4); n < NN; n += gridDim.x * 16) {
        bf16x8 u = *(const bf16x8*)&h[n * HD + c8];
#pragma unroll
        for (int i = 0; i < 8; i++) {
            float v = bf2f(u[i]);
            s[i] += v;
            sq[i] += v * v;
        }
    }
#pragma unroll
    for (int i = 0; i < 8; i++) {
        atomicAdd(&ls[c8 + i], s[i]);
        atomicAdd(&ls[HD + c8 + i], sq[i]);
    }
    __syncthreads();
    atomicAdd(&sums[t], ls[t]);
}

__global__ __launch_bounds__(128) void k_bn_fin(const float* __restrict__ sums,
                                                const float* __restrict__ gamma,
                                                const float* __restrict__ beta,
                                                float* __restrict__ ss) {
    int c = threadIdx.x;
    float inv_n = 1.0f / (float)NN;
    float mu = sums[c] * inv_n;
    float var = sums[HD + c] * inv_n - mu * mu;
    float sc = gamma[c] * rsqrtf(var + BN_EPS);
    ss[c] = sc;
    ss[HD + c] = beta[c] - mu * sc;
}

// ---------------- atomic-free pooling: one block per graph (float gfeat out) ----------------
__global__ __launch_bounds__(128) void k_pool_g(const unsigned short* __restrict__ h,
                                                const float* __restrict__ ss,
                                                const int* __restrict__ gstart,
                                                float* __restrict__ gfeat) {
    int g = blockIdx.x;
    int c = threadIdx.x;
    int n0 = gstart[g], n1 = gstart[g + 1];
    float sc = ss[c], sh = ss[HD + c];
    float s = 0.0f, mx = 0.0f;   // post-ReLU >= 0; 0 matches empty-seg guard
    for (int n = n0; n < n1; n++) {
        float v = fmaxf(bf2f(h[n * HD + c]) * sc + sh, 0.0f);
        s += v;
        mx = fmaxf(mx, v);
    }
    float cntf = (float)(n1 - n0);
    gfeat[g * 256 + c] = s / fmaxf(cntf, 1.0f);
    gfeat[g * 256 + HD + c] = mx;
}

// ---------------- MLP head v2: 8 graphs/block, 256 threads, split-K ----------------
__global__ __launch_bounds__(256) void k_mlp(const float* __restrict__ gfeat,
                                             const float* __restrict__ w1,
                                             const float* __restrict__ b1,
                                             const float* __restrict__ w2,
                                             const float* __restrict__ b2,
                                             const float* __restrict__ w3,
                                             const float* __restrict__ b3,
                                             float* __restrict__ out) {
    __shared__ float gs[8][258];    // 8 graphs x 256 feats (+2 pad)
    __shared__ float p1[8][130];    // L1 partial (upper K half)
    __shared__ float hs[8][130];    // h1
    __shared__ float p2[3][8][66];  // L2 partials (quarters 1..3)
    __shared__ float h2s[8][66];    // h2
    __shared__ float ps[64];
    int t = threadIdx.x;
    int g0 = blockIdx.x * 8;
    for (int f = t; f < 2048; f += 256) {
        int gi = f >> 8, k = f & 255;
        gs[gi][k] = gfeat[(g0 + gi) * 256 + k];
    }
    __syncthreads();
    // ---- L1: 128 cols x 2 K-halves (serial chain 128) ----
    {
        int colc = t & 127, half = t >> 7;
        int kb = half * 128;
        float acc[8] = {};
        for (int k = 0; k < 128; k++) {
            float w = w1[(kb + k) * HD + colc];
#pragma unroll
            for (int gi = 0; gi < 8; gi++) acc[gi] += gs[gi][kb + k] * w;  // broadcast read
        }
        if (half == 1) {
#pragma unroll
            for (int gi = 0; gi < 8; gi++) p1[gi][colc] = acc[gi];
        }
        __syncthreads();
        if (half == 0) {
            float bias = b1[colc];
#pragma unroll
            for (int gi = 0; gi < 8; gi++)
                hs[gi][colc] = fmaxf(acc[gi] + p1[gi][colc] + bias, 0.0f);
        }
    }
    __syncthreads();
    // ---- L2: 64 cols x 4 K-quarters (serial chain 32) ----
    {
        int colc = t & 63, q = t >> 6;
        int kb = q * 32;
        float acc[8] = {};
        for (int k = 0; k < 32; k++) {
            float w = w2[(kb + k) * 64 + colc];
#pragma unroll
            for (int gi = 0; gi < 8; gi++) acc[gi] += hs[gi][kb + k] * w;  // broadcast read
        }
        if (q > 0) {
#pragma unroll
            for (int gi = 0; gi < 8; gi++) p2[q - 1][gi][colc] = acc[gi];
        }
        __syncthreads();
        if (q == 0) {
            float bias = b2[colc];
#pragma unroll
            for (int gi = 0; gi < 8; gi++)
                h2s[gi][colc] = fmaxf(acc[gi] + p2[0][gi][colc] + p2[1][gi][colc]
                                      + p2[2][gi][colc] + bias, 0.0f);
        }
    }
    __syncthreads();
    // ---- L3: 8 lanes per graph ----
    if (t < 64) {
        int gi = t >> 3, prt = t & 7;
        float p = 0.0f;
#pragma unroll
        for (int k = 0; k < 8; k++) p += h2s[gi][prt * 8 + k] * w3[prt * 8 + k];
        ps[t] = p;
    }
    __syncthreads();
    if (t < 8) {
        float a = b3[0];
#pragma unroll
        for (int i = 0; i < 8; i++) a += ps[t * 8 + i];
        out[g0 + t] = a;
    }
}

extern "C" void kernel_launch(void* const* d_in, const int* in_sizes, int n_in,
                              void* d_out, int out_size, void* d_ws, size_t ws_size,
                              hipStream_t stream) {
    const float* x      = (const float*)d_in[0];
    const int*   eidx   = (const int*)d_in[1];   // [2, NE]: src then dst
    const int*   batch  = (const int*)d_in[2];
    const float* emb_W  = (const float*)d_in[3];
    const float* emb_b  = (const float*)d_in[4];
    const float* conv_W = (const float*)d_in[5];
    const float* conv_b = (const float*)d_in[6];
    const float* gamma  = (const float*)d_in[7];
    const float* beta   = (const float*)d_in[8];
    const float* w1     = (const float*)d_in[9];
    const float* b1     = (const float*)d_in[10];
    const float* w2     = (const float*)d_in[11];
    const float* b2     = (const float*)d_in[12];
    const float* w3     = (const float*)d_in[13];
    const float* b3     = (const float*)d_in[14];
    float* out = (float*)d_out;

    const int* src = eidx;
    const int* dst = eidx + NE;

    // workspace carve-up (R6-proven layout)
    unsigned short* A = (unsigned short*)d_ws;       // [NN*HD] bf16
    unsigned short* B = A + NN * HD;                 // [NN*HD] bf16
    float* dinv  = (float*)(B + NN * HD);            // [NN]
    float* bnsum = dinv + NN;                        // [256]
    float* bnss  = bnsum + 256;                      // [256]
    float* gfeat = bnss + 256;                       // [NG*256] float
    int*   gstart= (int*)(gfeat + NG * 256);         // [NG+1]
    int*   degi  = gstart + NG + 1;                  // [NN]
    int*   cursor= degi + NN;                        // [NN] (contiguous, 1 memset)
    int*   rowptr= cursor + NN;                      // [NN+1]
    int*   part  = rowptr + NN + 1;                  // [NSCAN]
    int*   col   = part + NSCAN;                     // [NE]
    unsigned short* WfE = (unsigned short*)(col + NE);  // [12288]
    unsigned short* WfC = WfE + 12288;                  // [3*16384]

    // ---- CSR build + dinv + graph bounds + weight pack ----
    (void)hipMemsetAsync(degi, 0, 2 * NN * sizeof(int), stream);  // degi + cursor
    k_hist<<<(NE + 255) / 256, 256, 0, stream>>>(dst, degi);
    k_scan1<<<NSCAN, 256, 0, stream>>>(degi, part);
    k_scan2<<<1, 512, 0, stream>>>(part);
    k_scan3<<<NSCAN, 256, 0, stream>>>(degi, part, rowptr, dinv);
    k_fill<<<(NE + 255) / 256, 256, 0, stream>>>(src, dst, rowptr, cursor, col);
    k_bounds<<<(NN + 255) / 256, 256, 0, stream>>>(batch, gstart);
    k_wpack<<<240, 256, 0, stream>>>(emb_W, conv_W, WfE, WfC);

    // ---- embedding (bf16 out) ----
    k_emb<<<NN / 32, 256, 0, stream>>>(x, WfE, emb_b, A);

    for (int l = 0; l < NL; l++) {
        if (l == 0)
            k_conv<false><<<NN / 32, 256, 0, stream>>>(A, nullptr, WfC, dinv, B);
        else
            k_conv<true><<<NN / 32, 256, 0, stream>>>(A, bnss, WfC + l * 16384, dinv, B);
        k_gather<<<NN / 16, 256, 0, stream>>>(rowptr, col, dinv, B, conv_b + l * HD, A);
        (void)hipMemsetAsync(bnsum, 0, 256 * sizeof(float), stream);
        k_bn_stats<<<512, 256, 0, stream>>>(A, bnsum);
        k_bn_fin<<<1, 128, 0, stream>>>(bnsum, gamma + l * HD, beta + l * HD, bnss);
    }

    // ---- pooling (BN of last layer fused, no atomics, float out) ----
    k_pool_g<<<NG, 128, 0, stream>>>(A, bnss, gstart, gfeat);

    // ---- MLP head v2 ----
    k_mlp<<<NG / 8, 256, 0, stream>>>(gfeat, w1, b1, w2, b2, w3, b3, out);
}